// Round 6
// baseline (270.450 us; speedup 1.0000x reference)
//
#include <hip/hip_runtime.h>

typedef unsigned short u16;
typedef unsigned int   u32;
typedef __bf16 bf16x8 __attribute__((ext_vector_type(8)));
typedef float  f32x4  __attribute__((ext_vector_type(4)));
typedef u16    u16x4  __attribute__((ext_vector_type(4)));
typedef u16    u16x8  __attribute__((ext_vector_type(8)));

#define BB 64
#define SS 256
#define HDIM 512
#define NHEAD 8
#define BS (BB*SS)            /* 16384 */
#define NBH 512

__device__ __forceinline__ u16 f2bf(float f){
    u32 u = __builtin_bit_cast(u32, f);
    u32 r = u + 0x7FFFu + ((u>>16)&1u);
    return (u16)(r>>16);
}
__device__ __forceinline__ float bf2f(u16 u){
    return __builtin_bit_cast(float, (u32)u<<16);
}
__device__ __forceinline__ void gload16(const void* g, void* l){
    __builtin_amdgcn_global_load_lds(
        (const __attribute__((address_space(1))) void*)g,
        (__attribute__((address_space(3))) void*)l, 16, 0, 0);
}

// QZ/KZ row layout: [bh][s] rows of 384B; elem d at byte ((d*2) ^ ((s&7)<<4))
__device__ __forceinline__ size_t zrow(int bh, int s){
    return ((size_t)bh*256 + s)*384;
}

// weights -> bf16 arena (u16 offsets): Wq@0 Wk@262144 Wv@524288 Wqp@786432
// Wkp@1048576 Wqa@1310720 Wka@1441792 Wd@1572864
__global__ __launch_bounds__(256) void cvtW_k(
    const float* __restrict__ Wq,  const float* __restrict__ Wk,
    const float* __restrict__ Wv,  const float* __restrict__ Wqp,
    const float* __restrict__ Wkp, const float* __restrict__ Wqa,
    const float* __restrict__ Wka, const float* __restrict__ Wd,
    u16* __restrict__ dst)
{
    const int i = blockIdx.x*256 + threadIdx.x;   // 229376 threads
    const float* s; u16* d; int local;
    if (i < 163840) {
        const int seg = i >> 15; local = i & 32767;
        s = seg==0?Wq:seg==1?Wk:seg==2?Wv:seg==3?Wqp:Wkp;
        d = dst + (size_t)seg*262144;
    } else if (i < 196608) {
        const int j = i - 163840; const int seg = j >> 14; local = j & 16383;
        s = seg ? Wka : Wqa;
        d = dst + 1310720 + (size_t)seg*131072;
    } else {
        local = i - 196608;
        s = Wd; d = dst + 1572864;
    }
    f32x4 a = ((const f32x4*)s)[local*2];
    f32x4 b = ((const f32x4*)s)[local*2+1];
    u16x8 o = { f2bf(a[0]),f2bf(a[1]),f2bf(a[2]),f2bf(a[3]),
                f2bf(b[0]),f2bf(b[1]),f2bf(b[2]),f2bf(b[3]) };
    ((u16x8*)d)[local] = o;
}

// fw1 f32 [256][256] -> bf16 pre-swizzled [row][256] (XOR (row&7)<<4 on bytes)
__global__ __launch_bounds__(64) void prep_fw1(const float* __restrict__ fw1,
                                               u16* __restrict__ fw1b)
{
    const int row = blockIdx.x;
    const int c0  = threadIdx.x * 4;
    float4 v = *(const float4*)(fw1 + (size_t)row*256 + c0);
    u16x4 pk = { f2bf(v.x), f2bf(v.y), f2bf(v.z), f2bf(v.w) };
    *(u16x4*)((char*)fw1b + (size_t)row*512 + ((c0*2) ^ ((row&7)<<4))) = pk;
}

// ---------------------------------------------------------------------------
// 128x128 tile GEMM, BK=64, 4 waves.
// AF32=0: A bf16 via global_load_lds.  AF32=1: A f32, inline f2bf reg-staging
//   (fuses the old cvt_k pass into the GEMM; B path & epilogues untouched).
// B: bf16 weights via global_load_lds (L2-hot).
// OUTMODE 2: f32 out o0 = acc + b0 + resid
// OUTMODE 4: QKV router (N=1536)  OUTMODE 5: QP/KP  OUTMODE 6: attr
// ---------------------------------------------------------------------------
template<int OUTMODE, int AF32>
__global__ __launch_bounds__(256,3) void gemm128(
    const void* __restrict__ Av, const u16* __restrict__ B,
    void* __restrict__ o0, void* __restrict__ o1, void* __restrict__ o2,
    const float* __restrict__ b0, const float* __restrict__ b1,
    const float* __restrict__ b2, const float* __restrict__ resid,
    int N, int K)
{
    __shared__ char sA[16384];
    __shared__ char sB[16384];
    const int tid = threadIdx.x, lane = tid & 63, w = tid >> 6;
    const int wr = (w & 1) * 64, wc = (w >> 1) * 64;
    const int flat = blockIdx.x;
    const int xcd = flat & 7, bi2 = flat >> 3;
    const int n_i = bi2 >> 4, mIn = bi2 & 15;
    const int m0 = (xcd*16 + mIn)*128, n0 = n_i*128;

    f32x4 acc[4][4];
    #pragma unroll
    for (int mi = 0; mi < 4; mi++)
        #pragma unroll
        for (int ni = 0; ni < 4; ni++) acc[mi][ni] = (f32x4){0.f,0.f,0.f,0.f};

    for (int k0 = 0; k0 < K; k0 += 64) {
        __syncthreads();
        if (AF32) {
            const float* A = (const float*)Av;
            const int r = tid >> 1, cseg = (tid & 1) * 32;
            const float* p = A + (size_t)(m0 + r)*K + k0 + cseg;
            alignas(16) u16 tmp[32];
            #pragma unroll
            for (int j = 0; j < 8; j++) {
                float4 fv = ((const float4*)p)[j];
                tmp[j*4+0]=f2bf(fv.x); tmp[j*4+1]=f2bf(fv.y);
                tmp[j*4+2]=f2bf(fv.z); tmp[j*4+3]=f2bf(fv.w);
            }
            const int rx = (r&7)<<4;
            #pragma unroll
            for (int j = 0; j < 4; j++)
                *(u16x8*)(sA + r*128 + ((cseg*2 + j*16) ^ rx)) = *(u16x8*)(tmp + j*8);
        } else {
            const u16* A = (const u16*)Av;
            #pragma unroll
            for (int i = 0; i < 4; i++) {
                const int off = w*4096 + i*1024 + lane*16;
                const int r = off >> 7, c = off & 0x70;
                gload16(A + (size_t)(m0 + r)*K + k0 + ((c ^ ((r&7)<<4)) >> 1),
                        sA + w*4096 + i*1024);
            }
        }
        #pragma unroll
        for (int i = 0; i < 4; i++) {
            const int off = w*4096 + i*1024 + lane*16;
            const int r = off >> 7, c = off & 0x70;
            gload16(B + (size_t)(n0 + r)*K + k0 + ((c ^ ((r&7)<<4)) >> 1),
                    sB + w*4096 + i*1024);
        }
        __syncthreads();
        #pragma unroll
        for (int ks = 0; ks < 2; ks++) {
            const int kb = ks*64 + (lane>>4)*16;
            bf16x8 af[4], bf[4];
            #pragma unroll
            for (int mi = 0; mi < 4; mi++) {
                const int r = wr + mi*16 + (lane&15);
                af[mi] = *(const bf16x8*)(sA + r*128 + (kb ^ ((r&7)<<4)));
            }
            #pragma unroll
            for (int ni = 0; ni < 4; ni++) {
                const int r = wc + ni*16 + (lane&15);
                bf[ni] = *(const bf16x8*)(sB + r*128 + (kb ^ ((r&7)<<4)));
            }
            #pragma unroll
            for (int mi = 0; mi < 4; mi++)
                #pragma unroll
                for (int ni = 0; ni < 4; ni++)
                    acc[mi][ni] = __builtin_amdgcn_mfma_f32_16x16x32_bf16(
                        af[mi], bf[ni], acc[mi][ni], 0,0,0);
        }
    }
    #pragma unroll
    for (int mi = 0; mi < 4; mi++) {
        const int rowb = m0 + wr + mi*16 + (lane>>4)*4;
        const int bi = rowb >> 8, s0 = rowb & 255;
        #pragma unroll
        for (int ni = 0; ni < 4; ni++) {
            const int gn = n0 + wc + ni*16 + (lane&15);
            if (OUTMODE == 2) {
                float* out = (float*)o0;
                const float bb = b0[gn];
                #pragma unroll
                for (int r = 0; r < 4; r++) {
                    size_t idx = (size_t)(rowb+r)*N + gn;
                    out[idx] = acc[mi][ni][r] + bb + resid[idx];
                }
            } else if (OUTMODE == 4) {
                const int seg = gn >> 9, o = gn & 511;
                const int hh = o >> 6, d = o & 63;
                const float bb = (seg==0?b0:seg==1?b1:b2)[o];
                const int bh = bi*8 + hh;
                if (seg < 2) {
                    char* outp = (char*)(seg ? o1 : o0);
                    #pragma unroll
                    for (int r = 0; r < 4; r++) {
                        const int s = s0 + r;
                        *(u16*)(outp + zrow(bh,s) + ((d*2) ^ ((s&7)<<4)))
                            = f2bf(acc[mi][ni][r] + bb);
                    }
                } else {
                    u16x4 pk;
                    #pragma unroll
                    for (int r = 0; r < 4; r++) pk[r] = f2bf(acc[mi][ni][r] + bb);
                    *(u16x4*)((char*)o2 + (size_t)bh*32768 + d*512
                                        + ((s0*2) ^ ((d&7)<<4))) = pk;
                }
            } else if (OUTMODE == 5) {
                const int seg = gn >> 9, o = gn & 511;
                const int hh = o >> 6, d = o & 63;
                const float bb = (seg ? b1 : b0)[o];
                const int bh = bi*8 + hh;
                char* outp = (char*)(seg ? o1 : o0);
                #pragma unroll
                for (int r = 0; r < 4; r++) {
                    const int s = s0 + r;
                    *(u16*)(outp + zrow(bh,s) + (((64+d)*2) ^ ((s&7)<<4)))
                        = f2bf(acc[mi][ni][r] + bb);
                }
            } else { // 6: attr
                const int qk = gn >> 9, fo = gn & 511;
                const int f = fo >> 8, o = fo & 255;
                const int hh = o >> 5, d = o & 31;
                const int cb = 128 + f*32;
                const float bb = (qk ? b1 : b0)[fo];
                const int bh = bi*8 + hh;
                char* outp = (char*)(qk ? o1 : o0);
                #pragma unroll
                for (int r = 0; r < 4; r++) {
                    const int s = s0 + r;
                    *(u16*)(outp + zrow(bh,s) + (((cb+d)*2) ^ ((s&7)<<4)))
                        = f2bf(acc[mi][ni][r] + bb);
                }
            }
        }
    }
}

// ---------------------------------------------------------------------------
// K34B: merged K' + energy, split 2 blocks per bh by SOURCE-PAIR.
//   sp0: local d 0..63 = item (gd 0..63),   64..95 = attr0 (gd 128..159)
//   sp1: local d 0..63 = pos  (gd 64..127), 64..95 = attr1 (gd 160..191)
// 512 threads (8 waves), ~78KB LDS -> 2 blocks/CU (barrier overlap).
// ---------------------------------------------------------------------------
#define K34B_QZ   53248
#define K34B_QZSZ 13312
#define K34B_SMEM (53248 + 2*13312)   /* 79872 */

__global__ __launch_bounds__(512,4) void k34b(
    const u16* __restrict__ QZ, const u16* __restrict__ KZ,
    const u16* __restrict__ fw1b, const float* __restrict__ fb1,
    const float* __restrict__ fw2, float* __restrict__ e)
{
    extern __shared__ char sm[];
    const int tid = threadIdx.x, lane = tid & 63, w = tid >> 6;   // w 0..7
    const int bh = blockIdx.x >> 1, sp = blockIdx.x & 1;
    const int l15 = lane & 15, lq = lane >> 4;
    const int base0 = sp ? 64 : 0;      // gd base for local d 0..63
    const int base1 = sp ? 160 : 128;   // gd base for local d 64..95

    // stage one 64-row QZ tile (our 96 d cols) into R1 buf: 832 16B chunks
    auto stage_qz = [&](int qt4, int buf) {
        char* dst = sm + K34B_QZ + buf*K34B_QZSZ;
        {
            const int li = w*64 + lane;
            const int q = li / 13, c = li - q*13;
            const int cc = (c == 12) ? 0 : c;        // pad chunk: dup-load c0
            const int ld = cc*8;
            const int gd = (ld < 64) ? base0 + ld : base1 + (ld - 64);
            gload16((const char*)QZ + zrow(bh, qt4*64 + q)
                        + ((gd*2) ^ ((q&7)<<4)),
                    dst + w*1024);
        }
        if (w < 5) {
            const int li = 512 + w*64 + lane;
            const int q = li / 13, c = li - q*13;
            const int cc = (c == 12) ? 0 : c;
            const int ld = cc*8;
            const int gd = (ld < 64) ? base0 + ld : base1 + (ld - 64);
            gload16((const char*)QZ + zrow(bh, qt4*64 + q)
                        + ((gd*2) ^ ((q&7)<<4)),
                    dst + 8192 + w*1024);
        }
    };

    // ---- prefetch QZ tile 0 (async), then stage KZT-half [96 d][512B swz]
    stage_qz(0, 0);
    {
        const int spair = tid & 127, dg = tid >> 7;   // 128 s-pairs x 4 d-grps
        const int s0 = spair*2;
        const char* r0 = (const char*)KZ + zrow(bh, s0);
        const char* r1 = (const char*)KZ + zrow(bh, s0+1);
        const int sw0 = (s0&7)<<4, sw1 = ((s0+1)&7)<<4;
        #pragma unroll
        for (int m = 0; m < 3; m++) {
            const int ld0 = dg*24 + m*8;
            const int gd = (ld0 < 64) ? base0 + ld0 : base1 + (ld0 - 64);
            u16x8 v0 = *(const u16x8*)(r0 + ((gd*2) ^ sw0));
            u16x8 v1 = *(const u16x8*)(r1 + ((gd*2) ^ sw1));
            #pragma unroll
            for (int ee = 0; ee < 8; ee++) {
                const int d = ld0 + ee;
                *(u32*)(sm + d*512 + ((s0*2) ^ ((d&7)<<4)))
                    = (u32)v0[ee] | ((u32)v1[ee] << 16);
            }
        }
    }
    __syncthreads();

    // ---- phase 1: K'-half. wave=(jb, dh): j rows jb*64..+63, d cols dh*48..+47
    const int jb = w & 3, dh = w >> 2;
    f32x4 kacc[4][3];
    #pragma unroll
    for (int js = 0; js < 4; js++)
        #pragma unroll
        for (int ni = 0; ni < 3; ni++) kacc[js][ni] = (f32x4){0.f,0.f,0.f,0.f};
    #pragma unroll
    for (int ks = 0; ks < 8; ks++) {
        const int kb = ks*64 + lq*16;
        bf16x8 a[4];
        #pragma unroll
        for (int js = 0; js < 4; js++) {
            const int ar = jb*64 + js*16 + l15;
            a[js] = *(const bf16x8*)((const char*)fw1b + (size_t)ar*512
                                     + (kb ^ ((l15&7)<<4)));
        }
        #pragma unroll
        for (int ni = 0; ni < 3; ni++) {
            const int dr = dh*48 + ni*16 + l15;
            bf16x8 b = *(const bf16x8*)(sm + dr*512 + (kb ^ ((dr&7)<<4)));
            #pragma unroll
            for (int js = 0; js < 4; js++)
                kacc[js][ni] = __builtin_amdgcn_mfma_f32_16x16x32_bf16(
                    a[js], b, kacc[js][ni], 0,0,0);
        }
    }
    __syncthreads();   // all KZT reads done; KP overlays R0

    // ---- KP write: [256 j][pitch 208] bf16, no swizzle (208 spreads banks)
    #pragma unroll
    for (int js = 0; js < 4; js++)
        #pragma unroll
        for (int ni = 0; ni < 3; ni++) {
            const int d = dh*48 + ni*16 + l15;
            #pragma unroll
            for (int r = 0; r < 4; r++) {
                const int j = jb*64 + js*16 + lq*4 + r;
                *(u16*)(sm + j*208 + d*2) = f2bf(kacc[js][ni][r]);
            }
        }
    __syncthreads();

    // ---- af2: wave=(jb, qh) owns same 64 j rows, full 96 d (3 ks of 32)
    const int qh = w >> 2;
    bf16x8 af2[4][3];
    #pragma unroll
    for (int js = 0; js < 4; js++) {
        const int ar = jb*64 + js*16 + l15;
        #pragma unroll
        for (int ks = 0; ks < 3; ks++)
            af2[js][ks] = *(const bf16x8*)(sm + ar*208 + ks*64 + lq*16);
    }
    float f1v[4][4], f2v[4][4];
    #pragma unroll
    for (int js = 0; js < 4; js++)
        #pragma unroll
        for (int r = 0; r < 4; r++) {
            const int j = jb*64 + js*16 + lq*4 + r;
            f1v[js][r] = fb1[j]; f2v[js][r] = fw2[j];
        }

    // ---- phase 2: qt loop, 1 barrier/iter; E slabs [4 jb][2 sl][256 q] f32
    for (int qt = 0; qt < 4; qt++) {
        __syncthreads();   // drains stage(qt); buf[(qt+1)&1] free; af2/KP done
        if (qt < 3) stage_qz(qt+1, (qt+1)&1);
        const char* qb = sm + K34B_QZ + (qt&1)*K34B_QZSZ;
        #pragma unroll
        for (int qs = 0; qs < 2; qs++) {
            const int qoff = (qh*32 + qs*16 + l15)*208 + lq*16;
            f32x4 acc[4];
            // sl = 0: ks 0,1 (64-d source)
            #pragma unroll
            for (int js = 0; js < 4; js++) acc[js] = (f32x4){0.f,0.f,0.f,0.f};
            #pragma unroll
            for (int kk = 0; kk < 2; kk++) {
                bf16x8 b = *(const bf16x8*)(qb + qoff + kk*64);
                #pragma unroll
                for (int js = 0; js < 4; js++)
                    acc[js] = __builtin_amdgcn_mfma_f32_16x16x32_bf16(
                        af2[js][kk], b, acc[js], 0,0,0);
            }
            {
                float ep = 0.f;
                #pragma unroll
                for (int js = 0; js < 4; js++)
                    #pragma unroll
                    for (int r = 0; r < 4; r++)
                        ep += fmaxf(acc[js][r] + f1v[js][r], 0.f) * f2v[js][r];
                ep += __shfl_xor(ep, 16);
                ep += __shfl_xor(ep, 32);
                if (lane < 16)
                    ((float*)sm)[(jb*2 + 0)*256 + qt*64 + qh*32 + qs*16 + lane] = ep;
            }
            // sl = 1: ks 2 (32-d source)
            #pragma unroll
            for (int js = 0; js < 4; js++) acc[js] = (f32x4){0.f,0.f,0.f,0.f};
            {
                bf16x8 b = *(const bf16x8*)(qb + qoff + 128);
                #pragma unroll
                for (int js = 0; js < 4; js++)
                    acc[js] = __builtin_amdgcn_mfma_f32_16x16x32_bf16(
                        af2[js][2], b, acc[js], 0,0,0);
            }
            {
                float ep = 0.f;
                #pragma unroll
                for (int js = 0; js < 4; js++)
                    #pragma unroll
                    for (int r = 0; r < 4; r++)
                        ep += fmaxf(acc[js][r] + f1v[js][r], 0.f) * f2v[js][r];
                ep += __shfl_xor(ep, 16);
                ep += __shfl_xor(ep, 32);
                if (lane < 16)
                    ((float*)sm)[(jb*2 + 1)*256 + qt*64 + qh*32 + qs*16 + lane] = ep;
            }
        }
    }
    __syncthreads();
    {   // final reduce over 4 jb slabs; e src order: {item,pos,attr0,attr1}
        const int q = tid & 255, sl = tid >> 8;
        const float* el = (const float*)sm;
        float s = 0.f;
        #pragma unroll
        for (int j2 = 0; j2 < 4; j2++) s += el[(j2*2 + sl)*256 + q];
        const int gsrc = sl ? (2 + sp) : sp;
        e[((size_t)bh*256 + q)*4 + gsrc] = s;
    }
}

// ---------------------------------------------------------------------------
// K5B: gates -> mixed = (g.QZ) @ KZ^T -> row softmax -> PV -> ctx
// 52KB LDS -> 3 blocks/CU (12 waves/CU).
// ---------------------------------------------------------------------------
#define K5_KZ 24576
#define K5_VT 36864
#define K5_SMEM 53248

__global__ __launch_bounds__(256,3) void k5b(
    const u16* __restrict__ QZ, const u16* __restrict__ KZ,
    const u16* __restrict__ VT, const float* __restrict__ e,
    u16* __restrict__ ctx)
{
    extern __shared__ char sm[];
    const int tid = threadIdx.x, lane = tid & 63, w = tid >> 6;
    const int flat = blockIdx.x;
    const int xcd = flat & 7, idx = flat >> 3;   // idx < 256
    const int qt = idx & 3;
    const int bh = (idx >> 2) * 8 + xcd;
    const int q0 = qt*64;
    const int b = bh >> 3, h = bh & 7;
    const int kq16 = (lane>>4)*16;
    const char* QZc = (const char*)QZ + zrow(bh, q0);
    const char* KZc = (const char*)KZ + zrow(bh, 0);
    const char* VTc = (const char*)VT + (size_t)bh*32768;

    // initial staging: QZ 24KB + KZ chunk0 12KB + VT chunk0 8KB (verbatim)
    #pragma unroll
    for (int i = 0; i < 6; i++)
        gload16(QZc + i*4096 + tid*16, sm + i*4096 + tid*16);
    #pragma unroll
    for (int i = 0; i < 3; i++)
        gload16(KZc + i*4096 + tid*16, sm + K5_KZ + i*4096 + tid*16);
    #pragma unroll
    for (int i = 0; i < 2; i++)
        gload16(VTc + i*4096 + tid*16, sm + K5_VT + i*4096 + tid*16);
    __syncthreads();

    const int qrow = w*16 + (lane&15);
    float ga[4];
    {
        f32x4 ev = *(const f32x4*)(e + ((size_t)bh*256 + q0 + qrow)*4);
        float em = fmaxf(fmaxf(ev[0],ev[1]), fmaxf(ev[2],ev[3]));
        float s = 0.f;
        #pragma unroll
        for (int j = 0; j < 4; j++) { ga[j] = __expf(ev[j]-em); s += ga[j]; }
        const float gi = 1.f / s;
        #pragma unroll
        for (int j = 0; j < 4; j++) ga[j] *= gi;
    }
    const int asw = ((lane&15)&7) << 4;
    bf16x8 aF[6];
    #pragma unroll
    for (int ks = 0; ks < 6; ks++) {
        const int sidx = (ks<2)?0:(ks<4)?1:(ks<5)?2:3;
        u16x8 v = *(const u16x8*)(sm + qrow*384 + ((ks*64 + kq16) ^ asw));
        const float gg = ga[sidx];
        u16x8 pk;
        #pragma unroll
        for (int j = 0; j < 8; j++) pk[j] = f2bf(bf2f(v[j]) * gg);
        aF[ks] = __builtin_bit_cast(bf16x8, pk);
    }

    // ---- QK^T over 8 chunks of 32 k-rows, reg-prefetch swap (T14)
    f32x4 macc[16];
    #pragma unroll
    for (int t = 0; t < 16; t++) macc[t] = (f32x4){0.f,0.f,0.f,0.f};
    u16x8 kreg[3];
    #pragma unroll
    for (int kt = 0; kt < 8; kt++) {
        if (kt < 7) {
            #pragma unroll
            for (int j = 0; j < 3; j++)
                kreg[j] = *(const u16x8*)(KZc + (size_t)(kt+1)*12288
                                          + (tid + j*256)*16);
        }
        #pragma unroll
        for (int n2 = 0; n2 < 2; n2++) {
            const int kr = n2*16 + (lane&15);
            const int ksw = (kr&7)<<4;
            #pragma unroll
            for (int ks = 0; ks < 6; ks++) {
                bf16x8 bb = *(const bf16x8*)(sm + K5_KZ + kr*384
                                             + ((ks*64 + kq16) ^ ksw));
                macc[kt*2+n2] = __builtin_amdgcn_mfma_f32_16x16x32_bf16(
                    aF[ks], bb, macc[kt*2+n2], 0,0,0);
            }
        }
        if (kt < 7) {
            __syncthreads();
            #pragma unroll
            for (int j = 0; j < 3; j++)
                *(u16x8*)(sm + K5_KZ + (tid + j*256)*16) = kreg[j];
            __syncthreads();
        }
    }
    __syncthreads();   // all waves done with KZ/QZ before probs overlay

    // ---- softmax + probs write [64 q][512B swz] overlaying [0,32768)
    #pragma unroll
    for (int rr = 0; rr < 4; rr++) {
        float mx = -3.4e38f;
        #pragma unroll
        for (int t = 0; t < 16; t++) mx = fmaxf(mx, macc[t][rr]);
        #pragma unroll
        for (int msk = 1; msk < 16; msk <<= 1) mx = fmaxf(mx, __shfl_xor(mx, msk));
        float s = 0.f;
        #pragma unroll
        for (int t = 0; t < 16; t++) {
            float pv = __expf((macc[t][rr] - mx) * 0.125f);
            macc[t][rr] = pv; s += pv;
        }
        #pragma unroll
        for (int msk = 1; msk < 16; msk <<= 1) s += __shfl_xor(s, msk);
        const float inv = 1.f / s;
        const int orow = w*16 + (lane>>4)*4 + rr;
        const int osw = (orow&7)<<4;
        #pragma unroll
        for (int t = 0; t < 16; t++) {
            const int col = t*16 + (lane&15);
            *(u16*)(sm + orow*512 + ((col*2) ^ osw)) = f2bf(macc[t][rr]*inv);
        }
    }
    __syncthreads();

    // ---- PV: probs a-frags in regs; VT d-tiles double-buffered
    bf16x8 a[8];
    const int prow = w*16 + (lane&15);
    const int psw = ((lane&15)&7)<<4;
    #pragma unroll
    for (int ks = 0; ks < 8; ks++)
        a[ks] = *(const bf16x8*)(sm + prow*512 + ((ks*64 + kq16) ^ psw));

    const int orow = w*16 + (lane>>4)*4;
    #pragma unroll
    for (int n = 0; n < 4; n++) {
        if (n < 3) {   // prefetch next VT d-tile into other buf
            #pragma unroll
            for (int i = 0; i < 2; i++)
                gload16(VTc + (size_t)(n+1)*8192 + i*4096 + tid*16,
                        sm + K5_VT + ((n+1)&1)*8192 + i*4096 + tid*16);
        }
        f32x4 pacc = (f32x4){0.f,0.f,0.f,0.f};
        const char* vb = sm + K5_VT + (n&1)*8192;
        const int dl = lane & 15;
        const int vsw = (dl&7)<<4;
        #pragma unroll
        for (int ks = 0; ks < 8; ks++) {
            bf16x8 bb = *(const bf16x8*)(vb + dl*512 + ((ks*64 + kq16) ^ vsw));
            pacc = __builtin_amdgcn_mfma_f32_16x16x32_bf16(a[ks], bb, pacc, 0,0,0);
        }
        {
            const int d = n*16 + dl;
            #pragma unroll
            for (int r = 0; r < 4; r++) {
                const size_t grow = (size_t)b*256 + q0 + orow + r;
                ctx[grow*512 + h*64 + d] = f2bf(pacc[r]);
            }
        }
        if (n < 3) __syncthreads();   // drain prefetch; free read buf
    }
}

// ---------------------------------------------------------------------------
__global__ __launch_bounds__(256) void ln_k(float* __restrict__ x,
    const float* __restrict__ gamma, const float* __restrict__ beta)
{
    const int row = blockIdx.x*4 + (threadIdx.x >> 6);
    const int l = threadIdx.x & 63;
    float* p = x + (size_t)row*HDIM;
    f32x4 v0 = *(const f32x4*)(p + l*4);
    f32x4 v1 = *(const f32x4*)(p + 256 + l*4);
    float s = v0[0]+v0[1]+v0[2]+v0[3] + v1[0]+v1[1]+v1[2]+v1[3];
    #pragma unroll
    for (int msk = 1; msk < 64; msk <<= 1) s += __shfl_xor(s, msk);
    const float mu = s * (1.f/512.f);
    float vs = 0.f;
    #pragma unroll
    for (int j = 0; j < 4; j++) {
        float d0 = v0[j]-mu, d1 = v1[j]-mu;
        vs += d0*d0 + d1*d1;
    }
    #pragma unroll
    for (int msk = 1; msk < 64; msk <<= 1) vs += __shfl_xor(vs, msk);
    const float inv = 1.f / sqrtf(vs * (1.f/512.f) + 1e-12f);
    f32x4 o0, o1;
    #pragma unroll
    for (int j = 0; j < 4; j++) {
        o0[j] = gamma[l*4+j]     * (v0[j]-mu) * inv + beta[l*4+j];
        o1[j] = gamma[256+l*4+j] * (v1[j]-mu) * inv + beta[256+l*4+j];
    }
    *(f32x4*)(p + l*4) = o0;
    *(f32x4*)(p + 256 + l*4) = o1;
}

// ---------------------------------------------------------------------------
extern "C" void kernel_launch(void* const* d_in, const int* in_sizes, int n_in,
                              void* d_out, int out_size, void* d_ws, size_t ws_size,
                              hipStream_t stream)
{
    const float* input = (const float*)d_in[0];
    const float* attrt = (const float*)d_in[1];
    const float* pose  = (const float*)d_in[2];
    const float* Wq  = (const float*)d_in[3];  const float* bq  = (const float*)d_in[4];
    const float* Wk  = (const float*)d_in[5];  const float* bk  = (const float*)d_in[6];
    const float* Wv  = (const float*)d_in[7];  const float* bv  = (const float*)d_in[8];
    const float* Wqp = (const float*)d_in[9];  const float* bqp = (const float*)d_in[10];
    const float* Wkp = (const float*)d_in[11]; const float* bkp = (const float*)d_in[12];
    const float* Wqa = (const float*)d_in[13]; const float* bqa = (const float*)d_in[14];
    const float* Wka = (const float*)d_in[15]; const float* bka = (const float*)d_in[16];
    const float* fw1 = (const float*)d_in[17]; const float* fb1 = (const float*)d_in[18];
    const float* fw2 = (const float*)d_in[19]; /* fb2 cancels in softmax */
    const float* Wd  = (const float*)d_in[21]; const float* bd  = (const float*)d_in[22];
    const float* gamma = (const float*)d_in[23]; const float* beta = (const float*)d_in[24];

    char* ws = (char*)d_ws;
    u16*   wsQZ  = (u16*)(ws);                      // 50,331,648 B
    u16*   wsKZ  = (u16*)(ws + 50331648);           // 50,331,648 B
    u16*   wsTmp = (u16*)(ws + 100663296);          // 16,777,216 B (ctx)
    float* wsE   = (float*)(ws + 117440512);        //  2,097,152 B
    u16*   fw1b  = (u16*)(ws + 119537664);          //    131,072 B
    u16*   dW    = (u16*)(ws + 119668736);          //  3,670,016 B (incl Wd)
    u16*   wsVT  = (u16*)d_out;                     // 16,777,216 B (dead before final GEMM)

    dim3 blk(256);

    cvtW_k<<<dim3(896), blk, 0, stream>>>(Wq, Wk, Wv, Wqp, Wkp, Wqa, Wka, Wd, dW);
    prep_fw1<<<dim3(256), dim3(64), 0, stream>>>(fw1, fw1b);

    // fused-cvt GEMMs: A = raw f32 activations (inline f2bf reg-staging),
    // B = bf16 weights via global_load_lds
    gemm128<6,1><<<dim3(1024), blk, 0, stream>>>(attrt, dW + 1310720,
        wsQZ, wsKZ, nullptr, bqa, bka, nullptr, nullptr, 1024, 256);
    gemm128<4,1><<<dim3(1536), blk, 0, stream>>>(input, dW,
        wsQZ, wsKZ, wsVT, bq, bk, bv, nullptr, 1536, 512);
    gemm128<5,1><<<dim3(1024), blk, 0, stream>>>(pose, dW + 786432,
        wsQZ, wsKZ, nullptr, bqp, bkp, nullptr, nullptr, 1024, 512);

    // merged K' + energy: 2 blocks per bh (source-pair split), 2 blocks/CU
    hipFuncSetAttribute(reinterpret_cast<const void*>(k34b),
                        hipFuncAttributeMaxDynamicSharedMemorySize, K34B_SMEM);
    k34b<<<dim3(NBH*2), dim3(512), K34B_SMEM, stream>>>(wsQZ, wsKZ, fw1b, fb1, fw2, wsE);

    hipFuncSetAttribute(reinterpret_cast<const void*>(k5b),
                        hipFuncAttributeMaxDynamicSharedMemorySize, K5_SMEM);
    k5b<<<dim3(2048), blk, K5_SMEM, stream>>>(wsQZ, wsKZ, wsVT, wsE, wsTmp);

    gemm128<2,0><<<dim3(512), blk, 0, stream>>>(wsTmp, dW + 1572864,
        d_out, nullptr, nullptr, bd, nullptr, nullptr, input, 512, 512);
    ln_k<<<dim3(BS/4), blk, 0, stream>>>((float*)d_out, gamma, beta);
}

// Round 7
// 264.181 us; speedup vs baseline: 1.0237x; 1.0237x over previous
//
#include <hip/hip_runtime.h>

typedef unsigned short u16;
typedef unsigned int   u32;
typedef __bf16 bf16x8 __attribute__((ext_vector_type(8)));
typedef float  f32x4  __attribute__((ext_vector_type(4)));
typedef u16    u16x4  __attribute__((ext_vector_type(4)));
typedef u16    u16x8  __attribute__((ext_vector_type(8)));

#define BB 64
#define SS 256
#define HDIM 512
#define NHEAD 8
#define BS (BB*SS)            /* 16384 */
#define NBH 512

__device__ __forceinline__ u16 f2bf(float f){
    u32 u = __builtin_bit_cast(u32, f);
    u32 r = u + 0x7FFFu + ((u>>16)&1u);
    return (u16)(r>>16);
}
__device__ __forceinline__ float bf2f(u16 u){
    return __builtin_bit_cast(float, (u32)u<<16);
}
__device__ __forceinline__ void gload16(const void* g, void* l){
    __builtin_amdgcn_global_load_lds(
        (const __attribute__((address_space(1))) void*)g,
        (__attribute__((address_space(3))) void*)l, 16, 0, 0);
}

// QZ/KZ row layout: [bh][s] rows of 384B; elem d at byte ((d*2) ^ ((s&7)<<4))
__device__ __forceinline__ size_t zrow(int bh, int s){
    return ((size_t)bh*256 + s)*384;
}

// ---------------------------------------------------------------------------
// f32 -> bf16 grid-stride converter (vec8)
// ---------------------------------------------------------------------------
__global__ __launch_bounds__(256) void cvt_k(const float* __restrict__ s,
                                             u16* __restrict__ d, int n8)
{
    int i = blockIdx.x*256 + threadIdx.x;
    const int stride = gridDim.x*256;
    for (; i < n8; i += stride) {
        f32x4 a = ((const f32x4*)s)[i*2];
        f32x4 b = ((const f32x4*)s)[i*2+1];
        u16x8 o = { f2bf(a[0]),f2bf(a[1]),f2bf(a[2]),f2bf(a[3]),
                    f2bf(b[0]),f2bf(b[1]),f2bf(b[2]),f2bf(b[3]) };
        ((u16x8*)d)[i] = o;
    }
}

// weights -> bf16 arena (u16 offsets): Wq@0 Wk@262144 Wv@524288 Wqp@786432
// Wkp@1048576 Wqa@1310720 Wka@1441792 Wd@1572864
__global__ __launch_bounds__(256) void cvtW_k(
    const float* __restrict__ Wq,  const float* __restrict__ Wk,
    const float* __restrict__ Wv,  const float* __restrict__ Wqp,
    const float* __restrict__ Wkp, const float* __restrict__ Wqa,
    const float* __restrict__ Wka, const float* __restrict__ Wd,
    u16* __restrict__ dst)
{
    const int i = blockIdx.x*256 + threadIdx.x;   // 229376 threads
    const float* s; u16* d; int local;
    if (i < 163840) {
        const int seg = i >> 15; local = i & 32767;
        s = seg==0?Wq:seg==1?Wk:seg==2?Wv:seg==3?Wqp:Wkp;
        d = dst + (size_t)seg*262144;
    } else if (i < 196608) {
        const int j = i - 163840; const int seg = j >> 14; local = j & 16383;
        s = seg ? Wka : Wqa;
        d = dst + 1310720 + (size_t)seg*131072;
    } else {
        local = i - 196608;
        s = Wd; d = dst + 1572864;
    }
    f32x4 a = ((const f32x4*)s)[local*2];
    f32x4 b = ((const f32x4*)s)[local*2+1];
    u16x8 o = { f2bf(a[0]),f2bf(a[1]),f2bf(a[2]),f2bf(a[3]),
                f2bf(b[0]),f2bf(b[1]),f2bf(b[2]),f2bf(b[3]) };
    ((u16x8*)d)[local] = o;
}

// fw1 f32 [256][256] -> bf16 pre-swizzled [row][256] (XOR (row&7)<<4 on bytes)
__global__ __launch_bounds__(64) void prep_fw1(const float* __restrict__ fw1,
                                               u16* __restrict__ fw1b)
{
    const int row = blockIdx.x;
    const int c0  = threadIdx.x * 4;
    float4 v = *(const float4*)(fw1 + (size_t)row*256 + c0);
    u16x4 pk = { f2bf(v.x), f2bf(v.y), f2bf(v.z), f2bf(v.w) };
    *(u16x4*)((char*)fw1b + (size_t)row*512 + ((c0*2) ^ ((row&7)<<4))) = pk;
}

// ---------------------------------------------------------------------------
// 128x128 tile GEMM, BK=64, 4 waves, global_load_lds staging.
// Grid: 1D, XCD-banded raster.
// OUTMODE 2: f32 out o0 = acc + b0 + resid
// OUTMODE 4: QKV router (N=1536)  OUTMODE 5: QP/KP  OUTMODE 6: attr
// ---------------------------------------------------------------------------
template<int OUTMODE, int BBF16>
__global__ __launch_bounds__(256,3) void gemm128(
    const u16* __restrict__ A, const void* __restrict__ Bv,
    void* __restrict__ o0, void* __restrict__ o1, void* __restrict__ o2,
    const float* __restrict__ b0, const float* __restrict__ b1,
    const float* __restrict__ b2, const float* __restrict__ resid,
    int N, int K)
{
    __shared__ char sA[16384];
    __shared__ char sB[16384];
    const int tid = threadIdx.x, lane = tid & 63, w = tid >> 6;
    const int wr = (w & 1) * 64, wc = (w >> 1) * 64;
    const int flat = blockIdx.x;
    const int xcd = flat & 7, bi2 = flat >> 3;
    const int n_i = bi2 >> 4, mIn = bi2 & 15;
    const int m0 = (xcd*16 + mIn)*128, n0 = n_i*128;

    f32x4 acc[4][4];
    #pragma unroll
    for (int mi = 0; mi < 4; mi++)
        #pragma unroll
        for (int ni = 0; ni < 4; ni++) acc[mi][ni] = (f32x4){0.f,0.f,0.f,0.f};

    for (int k0 = 0; k0 < K; k0 += 64) {
        __syncthreads();
        #pragma unroll
        for (int i = 0; i < 4; i++) {
            const int off = w*4096 + i*1024 + lane*16;
            const int r = off >> 7, c = off & 0x70;
            gload16(A + (size_t)(m0 + r)*K + k0 + ((c ^ ((r&7)<<4)) >> 1),
                    sA + w*4096 + i*1024);
        }
        if (BBF16) {
            const u16* B = (const u16*)Bv;
            #pragma unroll
            for (int i = 0; i < 4; i++) {
                const int off = w*4096 + i*1024 + lane*16;
                const int r = off >> 7, c = off & 0x70;
                gload16(B + (size_t)(n0 + r)*K + k0 + ((c ^ ((r&7)<<4)) >> 1),
                        sB + w*4096 + i*1024);
            }
        } else {
            const float* B = (const float*)Bv;
            const int r = tid >> 1, cseg = (tid & 1) * 32;
            const float* p = B + (size_t)(n0 + r)*K + k0 + cseg;
            alignas(16) u16 tmp[32];
            #pragma unroll
            for (int j = 0; j < 8; j++) {
                float4 fv = ((const float4*)p)[j];
                tmp[j*4+0]=f2bf(fv.x); tmp[j*4+1]=f2bf(fv.y);
                tmp[j*4+2]=f2bf(fv.z); tmp[j*4+3]=f2bf(fv.w);
            }
            const int rx = (r&7)<<4;
            #pragma unroll
            for (int j = 0; j < 4; j++)
                *(u16x8*)(sB + r*128 + ((cseg*2 + j*16) ^ rx)) = *(u16x8*)(tmp + j*8);
        }
        __syncthreads();
        #pragma unroll
        for (int ks = 0; ks < 2; ks++) {
            const int kb = ks*64 + (lane>>4)*16;
            bf16x8 af[4], bf[4];
            #pragma unroll
            for (int mi = 0; mi < 4; mi++) {
                const int r = wr + mi*16 + (lane&15);
                af[mi] = *(const bf16x8*)(sA + r*128 + (kb ^ ((r&7)<<4)));
            }
            #pragma unroll
            for (int ni = 0; ni < 4; ni++) {
                const int r = wc + ni*16 + (lane&15);
                bf[ni] = *(const bf16x8*)(sB + r*128 + (kb ^ ((r&7)<<4)));
            }
            #pragma unroll
            for (int mi = 0; mi < 4; mi++)
                #pragma unroll
                for (int ni = 0; ni < 4; ni++)
                    acc[mi][ni] = __builtin_amdgcn_mfma_f32_16x16x32_bf16(
                        af[mi], bf[ni], acc[mi][ni], 0,0,0);
        }
    }
    #pragma unroll
    for (int mi = 0; mi < 4; mi++) {
        const int rowb = m0 + wr + mi*16 + (lane>>4)*4;
        const int bi = rowb >> 8, s0 = rowb & 255;
        #pragma unroll
        for (int ni = 0; ni < 4; ni++) {
            const int gn = n0 + wc + ni*16 + (lane&15);
            if (OUTMODE == 2) {
                float* out = (float*)o0;
                const float bb = b0[gn];
                #pragma unroll
                for (int r = 0; r < 4; r++) {
                    size_t idx = (size_t)(rowb+r)*N + gn;
                    out[idx] = acc[mi][ni][r] + bb + resid[idx];
                }
            } else if (OUTMODE == 4) {
                const int seg = gn >> 9, o = gn & 511;
                const int hh = o >> 6, d = o & 63;
                const float bb = (seg==0?b0:seg==1?b1:b2)[o];
                const int bh = bi*8 + hh;
                if (seg < 2) {
                    char* outp = (char*)(seg ? o1 : o0);
                    #pragma unroll
                    for (int r = 0; r < 4; r++) {
                        const int s = s0 + r;
                        *(u16*)(outp + zrow(bh,s) + ((d*2) ^ ((s&7)<<4)))
                            = f2bf(acc[mi][ni][r] + bb);
                    }
                } else {
                    u16x4 pk;
                    #pragma unroll
                    for (int r = 0; r < 4; r++) pk[r] = f2bf(acc[mi][ni][r] + bb);
                    *(u16x4*)((char*)o2 + (size_t)bh*32768 + d*512
                                        + ((s0*2) ^ ((d&7)<<4))) = pk;
                }
            } else if (OUTMODE == 5) {
                const int seg = gn >> 9, o = gn & 511;
                const int hh = o >> 6, d = o & 63;
                const float bb = (seg ? b1 : b0)[o];
                const int bh = bi*8 + hh;
                char* outp = (char*)(seg ? o1 : o0);
                #pragma unroll
                for (int r = 0; r < 4; r++) {
                    const int s = s0 + r;
                    *(u16*)(outp + zrow(bh,s) + (((64+d)*2) ^ ((s&7)<<4)))
                        = f2bf(acc[mi][ni][r] + bb);
                }
            } else { // 6: attr
                const int qk = gn >> 9, fo = gn & 511;
                const int f = fo >> 8, o = fo & 255;
                const int hh = o >> 5, d = o & 31;
                const int cb = 128 + f*32;
                const float bb = (qk ? b1 : b0)[fo];
                const int bh = bi*8 + hh;
                char* outp = (char*)(qk ? o1 : o0);
                #pragma unroll
                for (int r = 0; r < 4; r++) {
                    const int s = s0 + r;
                    *(u16*)(outp + zrow(bh,s) + (((cb+d)*2) ^ ((s&7)<<4)))
                        = f2bf(acc[mi][ni][r] + bb);
                }
            }
        }
    }
}

// ---------------------------------------------------------------------------
// K34B: merged K' + energy, split 2 blocks per bh by SOURCE-PAIR.
//   sp0: local d 0..63 = item (gd 0..63),   64..95 = attr0 (gd 128..159)
//   sp1: local d 0..63 = pos  (gd 64..127), 64..95 = attr1 (gd 160..191)
// 512 threads (8 waves), ~78KB LDS -> 2 blocks/CU (barrier overlap).
// ---------------------------------------------------------------------------
#define K34B_QZ   53248
#define K34B_QZSZ 13312
#define K34B_SMEM (53248 + 2*13312)   /* 79872 */

__global__ __launch_bounds__(512,4) void k34b(
    const u16* __restrict__ QZ, const u16* __restrict__ KZ,
    const u16* __restrict__ fw1b, const float* __restrict__ fb1,
    const float* __restrict__ fw2, float* __restrict__ e)
{
    extern __shared__ char sm[];
    const int tid = threadIdx.x, lane = tid & 63, w = tid >> 6;   // w 0..7
    const int bh = blockIdx.x >> 1, sp = blockIdx.x & 1;
    const int l15 = lane & 15, lq = lane >> 4;
    const int base0 = sp ? 64 : 0;      // gd base for local d 0..63
    const int base1 = sp ? 160 : 128;   // gd base for local d 64..95

    // stage one 64-row QZ tile (our 96 d cols) into R1 buf: 832 16B chunks
    auto stage_qz = [&](int qt4, int buf) {
        char* dst = sm + K34B_QZ + buf*K34B_QZSZ;
        {
            const int li = w*64 + lane;
            const int q = li / 13, c = li - q*13;
            const int cc = (c == 12) ? 0 : c;        // pad chunk: dup-load c0
            const int ld = cc*8;
            const int gd = (ld < 64) ? base0 + ld : base1 + (ld - 64);
            gload16((const char*)QZ + zrow(bh, qt4*64 + q)
                        + ((gd*2) ^ ((q&7)<<4)),
                    dst + w*1024);
        }
        if (w < 5) {
            const int li = 512 + w*64 + lane;
            const int q = li / 13, c = li - q*13;
            const int cc = (c == 12) ? 0 : c;
            const int ld = cc*8;
            const int gd = (ld < 64) ? base0 + ld : base1 + (ld - 64);
            gload16((const char*)QZ + zrow(bh, qt4*64 + q)
                        + ((gd*2) ^ ((q&7)<<4)),
                    dst + 8192 + w*1024);
        }
    };

    // ---- prefetch QZ tile 0 (async), then stage KZT-half [96 d][512B swz]
    stage_qz(0, 0);
    {
        const int spair = tid & 127, dg = tid >> 7;   // 128 s-pairs x 4 d-grps
        const int s0 = spair*2;
        const char* r0 = (const char*)KZ + zrow(bh, s0);
        const char* r1 = (const char*)KZ + zrow(bh, s0+1);
        const int sw0 = (s0&7)<<4, sw1 = ((s0+1)&7)<<4;
        #pragma unroll
        for (int m = 0; m < 3; m++) {
            const int ld0 = dg*24 + m*8;
            const int gd = (ld0 < 64) ? base0 + ld0 : base1 + (ld0 - 64);
            u16x8 v0 = *(const u16x8*)(r0 + ((gd*2) ^ sw0));
            u16x8 v1 = *(const u16x8*)(r1 + ((gd*2) ^ sw1));
            #pragma unroll
            for (int ee = 0; ee < 8; ee++) {
                const int d = ld0 + ee;
                *(u32*)(sm + d*512 + ((s0*2) ^ ((d&7)<<4)))
                    = (u32)v0[ee] | ((u32)v1[ee] << 16);
            }
        }
    }
    __syncthreads();

    // ---- phase 1: K'-half. wave=(jb, dh): j rows jb*64..+63, d cols dh*48..+47
    const int jb = w & 3, dh = w >> 2;
    f32x4 kacc[4][3];
    #pragma unroll
    for (int js = 0; js < 4; js++)
        #pragma unroll
        for (int ni = 0; ni < 3; ni++) kacc[js][ni] = (f32x4){0.f,0.f,0.f,0.f};
    #pragma unroll
    for (int ks = 0; ks < 8; ks++) {
        const int kb = ks*64 + lq*16;
        bf16x8 a[4];
        #pragma unroll
        for (int js = 0; js < 4; js++) {
            const int ar = jb*64 + js*16 + l15;
            a[js] = *(const bf16x8*)((const char*)fw1b + (size_t)ar*512
                                     + (kb ^ ((l15&7)<<4)));
        }
        #pragma unroll
        for (int ni = 0; ni < 3; ni++) {
            const int dr = dh*48 + ni*16 + l15;
            bf16x8 b = *(const bf16x8*)(sm + dr*512 + (kb ^ ((dr&7)<<4)));
            #pragma unroll
            for (int js = 0; js < 4; js++)
                kacc[js][ni] = __builtin_amdgcn_mfma_f32_16x16x32_bf16(
                    a[js], b, kacc[js][ni], 0,0,0);
        }
    }
    __syncthreads();   // all KZT reads done; KP overlays R0

    // ---- KP write: [256 j][pitch 208] bf16, no swizzle (208 spreads banks)
    #pragma unroll
    for (int js = 0; js < 4; js++)
        #pragma unroll
        for (int ni = 0; ni < 3; ni++) {
            const int d = dh*48 + ni*16 + l15;
            #pragma unroll
            for (int r = 0; r < 4; r++) {
                const int j = jb*64 + js*16 + lq*4 + r;
                *(u16*)(sm + j*208 + d*2) = f2bf(kacc[js][ni][r]);
            }
        }
    __syncthreads();

    // ---- af2: wave=(jb, qh) owns same 64 j rows, full 96 d (3 ks of 32)
    const int qh = w >> 2;
    bf16x8 af2[4][3];
    #pragma unroll
    for (int js = 0; js < 4; js++) {
        const int ar = jb*64 + js*16 + l15;
        #pragma unroll
        for (int ks = 0; ks < 3; ks++)
            af2[js][ks] = *(const bf16x8*)(sm + ar*208 + ks*64 + lq*16);
    }
    float f1v[4][4], f2v[4][4];
    #pragma unroll
    for (int js = 0; js < 4; js++)
        #pragma unroll
        for (int r = 0; r < 4; r++) {
            const int j = jb*64 + js*16 + lq*4 + r;
            f1v[js][r] = fb1[j]; f2v[js][r] = fw2[j];
        }

    // ---- phase 2: qt loop, 1 barrier/iter; E slabs [4 jb][2 sl][256 q] f32
    for (int qt = 0; qt < 4; qt++) {
        __syncthreads();   // drains stage(qt); buf[(qt+1)&1] free; af2/KP done
        if (qt < 3) stage_qz(qt+1, (qt+1)&1);
        const char* qb = sm + K34B_QZ + (qt&1)*K34B_QZSZ;
        #pragma unroll
        for (int qs = 0; qs < 2; qs++) {
            const int qoff = (qh*32 + qs*16 + l15)*208 + lq*16;
            f32x4 acc[4];
            // sl = 0: ks 0,1 (64-d source)
            #pragma unroll
            for (int js = 0; js < 4; js++) acc[js] = (f32x4){0.f,0.f,0.f,0.f};
            #pragma unroll
            for (int kk = 0; kk < 2; kk++) {
                bf16x8 b = *(const bf16x8*)(qb + qoff + kk*64);
                #pragma unroll
                for (int js = 0; js < 4; js++)
                    acc[js] = __builtin_amdgcn_mfma_f32_16x16x32_bf16(
                        af2[js][kk], b, acc[js], 0,0,0);
            }
            {
                float ep = 0.f;
                #pragma unroll
                for (int js = 0; js < 4; js++)
                    #pragma unroll
                    for (int r = 0; r < 4; r++)
                        ep += fmaxf(acc[js][r] + f1v[js][r], 0.f) * f2v[js][r];
                ep += __shfl_xor(ep, 16);
                ep += __shfl_xor(ep, 32);
                if (lane < 16)
                    ((float*)sm)[(jb*2 + 0)*256 + qt*64 + qh*32 + qs*16 + lane] = ep;
            }
            // sl = 1: ks 2 (32-d source)
            #pragma unroll
            for (int js = 0; js < 4; js++) acc[js] = (f32x4){0.f,0.f,0.f,0.f};
            {
                bf16x8 b = *(const bf16x8*)(qb + qoff + 128);
                #pragma unroll
                for (int js = 0; js < 4; js++)
                    acc[js] = __builtin_amdgcn_mfma_f32_16x16x32_bf16(
                        af2[js][2], b, acc[js], 0,0,0);
            }
            {
                float ep = 0.f;
                #pragma unroll
                for (int js = 0; js < 4; js++)
                    #pragma unroll
                    for (int r = 0; r < 4; r++)
                        ep += fmaxf(acc[js][r] + f1v[js][r], 0.f) * f2v[js][r];
                ep += __shfl_xor(ep, 16);
                ep += __shfl_xor(ep, 32);
                if (lane < 16)
                    ((float*)sm)[(jb*2 + 1)*256 + qt*64 + qh*32 + qs*16 + lane] = ep;
            }
        }
    }
    __syncthreads();
    {   // final reduce over 4 jb slabs; e src order: {item,pos,attr0,attr1}
        const int q = tid & 255, sl = tid >> 8;
        const float* el = (const float*)sm;
        float s = 0.f;
        #pragma unroll
        for (int j2 = 0; j2 < 4; j2++) s += el[(j2*2 + sl)*256 + q];
        const int gsrc = sl ? (2 + sp) : sp;
        e[((size_t)bh*256 + q)*4 + gsrc] = s;
    }
}

// ---------------------------------------------------------------------------
// K5C: gates -> mixed = (g.QZ) @ KZ^T -> row softmax -> PV -> ctx
// KZ B-fragments are SINGLE-USE -> read them directly from global (L2-hot,
// verbatim zrow layout; (t*16+l15)&7 == l15&7 so the XOR constant is shared
// with aF). Kills the 14 QK^T barriers + LDS round-trip entirely.
// LDS 48KB: probs [64 q][512B swz] in [0,32768) (overlays QZ tile after aF;
// one barrier guards the overlay) + VT dbuf 2x8KB at [32768,49152).
// ---------------------------------------------------------------------------
#define K5C_VT   32768
#define K5C_SMEM 49152

__global__ __launch_bounds__(256,3) void k5c(
    const u16* __restrict__ QZ, const u16* __restrict__ KZ,
    const u16* __restrict__ VT, const float* __restrict__ e,
    u16* __restrict__ ctx)
{
    extern __shared__ char sm[];
    const int tid = threadIdx.x, lane = tid & 63, w = tid >> 6;
    const int flat = blockIdx.x;
    const int xcd = flat & 7, idx = flat >> 3;   // idx < 256
    const int qt = idx & 3;
    const int bh = (idx >> 2) * 8 + xcd;
    const int q0 = qt*64;
    const int b = bh >> 3, h = bh & 7;
    const int l15 = lane & 15, kq16 = (lane>>4)*16;
    const char* QZc = (const char*)QZ + zrow(bh, q0);
    const char* KZc = (const char*)KZ + zrow(bh, 0);
    const char* VTc = (const char*)VT + (size_t)bh*32768;

    // initial staging: QZ tile 24KB + VT d-tile0 8KB (verbatim)
    #pragma unroll
    for (int i = 0; i < 6; i++)
        gload16(QZc + i*4096 + tid*16, sm + i*4096 + tid*16);
    #pragma unroll
    for (int i = 0; i < 2; i++)
        gload16(VTc + i*4096 + tid*16, sm + K5C_VT + i*4096 + tid*16);
    __syncthreads();

    const int qrow = w*16 + l15;
    float ga[4];
    {
        f32x4 ev = *(const f32x4*)(e + ((size_t)bh*256 + q0 + qrow)*4);
        float em = fmaxf(fmaxf(ev[0],ev[1]), fmaxf(ev[2],ev[3]));
        float s = 0.f;
        #pragma unroll
        for (int j = 0; j < 4; j++) { ga[j] = __expf(ev[j]-em); s += ga[j]; }
        const float gi = 1.f / s;
        #pragma unroll
        for (int j = 0; j < 4; j++) ga[j] *= gi;
    }
    const int asw = (l15 & 7) << 4;
    bf16x8 aF[6];
    #pragma unroll
    for (int ks = 0; ks < 6; ks++) {
        const int sidx = (ks<2)?0:(ks<4)?1:(ks<5)?2:3;
        u16x8 v = *(const u16x8*)(sm + qrow*384 + ((ks*64 + kq16) ^ asw));
        const float gg = ga[sidx];
        u16x8 pk;
        #pragma unroll
        for (int j = 0; j < 8; j++) pk[j] = f2bf(bf2f(v[j]) * gg);
        aF[ks] = __builtin_bit_cast(bf16x8, pk);
    }
    __syncthreads();   // all aF reads done; probs may overlay [0,32768)

    // ---- QK^T: 16 k-tiles of 16 rows, B-frags DIRECT from global, no barriers
    f32x4 macc[16];
    #pragma unroll
    for (int t = 0; t < 16; t++) macc[t] = (f32x4){0.f,0.f,0.f,0.f};
    #pragma unroll
    for (int t = 0; t < 16; t++) {
        const char* kp = KZc + (size_t)(t*16 + l15)*384;
        #pragma unroll
        for (int ks = 0; ks < 6; ks++) {
            bf16x8 bb = *(const bf16x8*)(kp + ((ks*64 + kq16) ^ asw));
            macc[t] = __builtin_amdgcn_mfma_f32_16x16x32_bf16(
                aF[ks], bb, macc[t], 0,0,0);
        }
    }

    // ---- softmax + probs write [64 q][512B swz] into [0,32768)
    #pragma unroll
    for (int rr = 0; rr < 4; rr++) {
        float mx = -3.4e38f;
        #pragma unroll
        for (int t = 0; t < 16; t++) mx = fmaxf(mx, macc[t][rr]);
        #pragma unroll
        for (int msk = 1; msk < 16; msk <<= 1) mx = fmaxf(mx, __shfl_xor(mx, msk));
        float s = 0.f;
        #pragma unroll
        for (int t = 0; t < 16; t++) {
            float pv = __expf((macc[t][rr] - mx) * 0.125f);
            macc[t][rr] = pv; s += pv;
        }
        #pragma unroll
        for (int msk = 1; msk < 16; msk <<= 1) s += __shfl_xor(s, msk);
        const float inv = 1.f / s;
        const int orow = w*16 + (lane>>4)*4 + rr;
        const int osw = (orow&7)<<4;
        #pragma unroll
        for (int t = 0; t < 16; t++) {
            const int col = t*16 + l15;
            *(u16*)(sm + orow*512 + ((col*2) ^ osw)) = f2bf(macc[t][rr]*inv);
        }
    }
    __syncthreads();

    // ---- PV: probs a-frags in regs; VT d-tiles double-buffered
    bf16x8 a[8];
    const int prow = w*16 + l15;
    #pragma unroll
    for (int ks = 0; ks < 8; ks++)
        a[ks] = *(const bf16x8*)(sm + prow*512 + ((ks*64 + kq16) ^ asw));

    const int orow = w*16 + (lane>>4)*4;
    #pragma unroll
    for (int n = 0; n < 4; n++) {
        if (n < 3) {   // prefetch next VT d-tile into other buf
            #pragma unroll
            for (int i = 0; i < 2; i++)
                gload16(VTc + (size_t)(n+1)*8192 + i*4096 + tid*16,
                        sm + K5C_VT + ((n+1)&1)*8192 + i*4096 + tid*16);
        }
        f32x4 pacc = (f32x4){0.f,0.f,0.f,0.f};
        const char* vb = sm + K5C_VT + (n&1)*8192;
        const int vsw = (l15&7)<<4;
        #pragma unroll
        for (int ks = 0; ks < 8; ks++) {
            bf16x8 bb = *(const bf16x8*)(vb + l15*512 + ((ks*64 + kq16) ^ vsw));
            pacc = __builtin_amdgcn_mfma_f32_16x16x32_bf16(a[ks], bb, pacc, 0,0,0);
        }
        {
            const int d = n*16 + l15;
            #pragma unroll
            for (int r = 0; r < 4; r++) {
                const size_t grow = (size_t)b*256 + q0 + orow + r;
                ctx[grow*512 + h*64 + d] = f2bf(pacc[r]);
            }
        }
        if (n < 3) __syncthreads();   // drain prefetch; free read buf
    }
}

// ---------------------------------------------------------------------------
__global__ __launch_bounds__(256) void ln_k(float* __restrict__ x,
    const float* __restrict__ gamma, const float* __restrict__ beta)
{
    const int row = blockIdx.x*4 + (threadIdx.x >> 6);
    const int l = threadIdx.x & 63;
    float* p = x + (size_t)row*HDIM;
    f32x4 v0 = *(const f32x4*)(p + l*4);
    f32x4 v1 = *(const f32x4*)(p + 256 + l*4);
    float s = v0[0]+v0[1]+v0[2]+v0[3] + v1[0]+v1[1]+v1[2]+v1[3];
    #pragma unroll
    for (int msk = 1; msk < 64; msk <<= 1) s += __shfl_xor(s, msk);
    const float mu = s * (1.f/512.f);
    float vs = 0.f;
    #pragma unroll
    for (int j = 0; j < 4; j++) {
        float d0 = v0[j]-mu, d1 = v1[j]-mu;
        vs += d0*d0 + d1*d1;
    }
    #pragma unroll
    for (int msk = 1; msk < 64; msk <<= 1) vs += __shfl_xor(vs, msk);
    const float inv = 1.f / sqrtf(vs * (1.f/512.f) + 1e-12f);
    f32x4 o0, o1;
    #pragma unroll
    for (int j = 0; j < 4; j++) {
        o0[j] = gamma[l*4+j]     * (v0[j]-mu) * inv + beta[l*4+j];
        o1[j] = gamma[256+l*4+j] * (v1[j]-mu) * inv + beta[256+l*4+j];
    }
    *(f32x4*)(p + l*4) = o0;
    *(f32x4*)(p + 256 + l*4) = o1;
}

// ---------------------------------------------------------------------------
extern "C" void kernel_launch(void* const* d_in, const int* in_sizes, int n_in,
                              void* d_out, int out_size, void* d_ws, size_t ws_size,
                              hipStream_t stream)
{
    const float* input = (const float*)d_in[0];
    const float* attrt = (const float*)d_in[1];
    const float* pose  = (const float*)d_in[2];
    const float* Wq  = (const float*)d_in[3];  const float* bq  = (const float*)d_in[4];
    const float* Wk  = (const float*)d_in[5];  const float* bk  = (const float*)d_in[6];
    const float* Wv  = (const float*)d_in[7];  const float* bv  = (const float*)d_in[8];
    const float* Wqp = (const float*)d_in[9];  const float* bqp = (const float*)d_in[10];
    const float* Wkp = (const float*)d_in[11]; const float* bkp = (const float*)d_in[12];
    const float* Wqa = (const float*)d_in[13]; const float* bqa = (const float*)d_in[14];
    const float* Wka = (const float*)d_in[15]; const float* bka = (const float*)d_in[16];
    const float* fw1 = (const float*)d_in[17]; const float* fb1 = (const float*)d_in[18];
    const float* fw2 = (const float*)d_in[19]; /* fb2 cancels in softmax */
    const float* Wd  = (const float*)d_in[21]; const float* bd  = (const float*)d_in[22];
    const float* gamma = (const float*)d_in[23]; const float* beta = (const float*)d_in[24];

    char* ws = (char*)d_ws;
    u16*   wsQZ  = (u16*)(ws);                      // 50,331,648 B
    u16*   wsKZ  = (u16*)(ws + 50331648);           // 50,331,648 B
    u16*   wsTmp = (u16*)(ws + 100663296);          // 16,777,216 B (inB/poseB -> ctx)
    float* wsE   = (float*)(ws + 117440512);        //  2,097,152 B
    u16*   fw1b  = (u16*)(ws + 119537664);          //    131,072 B
    u16*   dW    = (u16*)(ws + 119668736);          //  3,670,016 B (incl Wd)
    u16*   wsVT  = (u16*)d_out;                     // 16,777,216 B (dead before final GEMM)

    dim3 blk(256);

    cvtW_k<<<dim3(896), blk, 0, stream>>>(Wq, Wk, Wv, Wqp, Wkp, Wqa, Wka, Wd, dW);
    prep_fw1<<<dim3(256), dim3(64), 0, stream>>>(fw1, fw1b);

    cvt_k<<<dim3(2048), blk, 0, stream>>>(attrt, wsTmp, 524288);
    gemm128<6,1><<<dim3(1024), blk, 0, stream>>>(wsTmp, dW + 1310720,
        wsQZ, wsKZ, nullptr, bqa, bka, nullptr, nullptr, 1024, 256);
    cvt_k<<<dim3(2048), blk, 0, stream>>>(input, wsTmp, 1048576);
    gemm128<4,1><<<dim3(1536), blk, 0, stream>>>(wsTmp, dW,
        wsQZ, wsKZ, wsVT, bq, bk, bv, nullptr, 1536, 512);
    cvt_k<<<dim3(2048), blk, 0, stream>>>(pose, wsTmp, 1048576);
    gemm128<5,1><<<dim3(1024), blk, 0, stream>>>(wsTmp, dW + 786432,
        wsQZ, wsKZ, nullptr, bqp, bkp, nullptr, nullptr, 1024, 512);

    // merged K' + energy: 2 blocks per bh (source-pair split), 2 blocks/CU
    hipFuncSetAttribute(reinterpret_cast<const void*>(k34b),
                        hipFuncAttributeMaxDynamicSharedMemorySize, K34B_SMEM);
    k34b<<<dim3(NBH*2), dim3(512), K34B_SMEM, stream>>>(wsQZ, wsKZ, fw1b, fb1, fw2, wsE);

    hipFuncSetAttribute(reinterpret_cast<const void*>(k5c),
                        hipFuncAttributeMaxDynamicSharedMemorySize, K5C_SMEM);
    k5c<<<dim3(2048), blk, K5C_SMEM, stream>>>(wsQZ, wsKZ, wsVT, wsE, wsTmp);

    gemm128<2,1><<<dim3(512), blk, 0, stream>>>(wsTmp, dW + 1572864,
        d_out, nullptr, nullptr, bd, nullptr, nullptr, input, 512, 512);
    ln_k<<<dim3(BS/4), blk, 0, stream>>>((float*)d_out, gamma, beta);
}

// Round 8
// 234.814 us; speedup vs baseline: 1.1518x; 1.1251x over previous
//
#include <hip/hip_runtime.h>

typedef unsigned short u16;
typedef unsigned int   u32;
typedef __bf16 bf16x8 __attribute__((ext_vector_type(8)));
typedef float  f32x4  __attribute__((ext_vector_type(4)));
typedef u16    u16x4  __attribute__((ext_vector_type(4)));
typedef u16    u16x8  __attribute__((ext_vector_type(8)));

#define BB 64
#define SS 256
#define HDIM 512
#define NHEAD 8
#define BS (BB*SS)            /* 16384 */
#define NBH 512

__device__ __forceinline__ u16 f2bf(float f){
    u32 u = __builtin_bit_cast(u32, f);
    u32 r = u + 0x7FFFu + ((u>>16)&1u);
    return (u16)(r>>16);
}
__device__ __forceinline__ float bf2f(u16 u){
    return __builtin_bit_cast(float, (u32)u<<16);
}
__device__ __forceinline__ void gload16(const void* g, void* l){
    __builtin_amdgcn_global_load_lds(
        (const __attribute__((address_space(1))) void*)g,
        (__attribute__((address_space(3))) void*)l, 16, 0, 0);
}

// QZ/KZ row layout: [bh][s] rows of 384B; elem d at byte ((d*2) ^ ((s&7)<<4))
__device__ __forceinline__ size_t zrow(int bh, int s){
    return ((size_t)bh*256 + s)*384;
}

// ---------------------------------------------------------------------------
// f32 -> bf16 grid-stride converter (vec8)
// ---------------------------------------------------------------------------
__global__ __launch_bounds__(256) void cvt_k(const float* __restrict__ s,
                                             u16* __restrict__ d, int n8)
{
    int i = blockIdx.x*256 + threadIdx.x;
    const int stride = gridDim.x*256;
    for (; i < n8; i += stride) {
        f32x4 a = ((const f32x4*)s)[i*2];
        f32x4 b = ((const f32x4*)s)[i*2+1];
        u16x8 o = { f2bf(a[0]),f2bf(a[1]),f2bf(a[2]),f2bf(a[3]),
                    f2bf(b[0]),f2bf(b[1]),f2bf(b[2]),f2bf(b[3]) };
        ((u16x8*)d)[i] = o;
    }
}

// weights -> bf16 arena (u16 offsets): Wq@0 Wk@262144 Wv@524288 Wqp@786432
// Wkp@1048576 Wqa@1310720 Wka@1441792 Wd@1572864
__global__ __launch_bounds__(256) void cvtW_k(
    const float* __restrict__ Wq,  const float* __restrict__ Wk,
    const float* __restrict__ Wv,  const float* __restrict__ Wqp,
    const float* __restrict__ Wkp, const float* __restrict__ Wqa,
    const float* __restrict__ Wka, const float* __restrict__ Wd,
    u16* __restrict__ dst)
{
    const int i = blockIdx.x*256 + threadIdx.x;   // 229376 threads
    const float* s; u16* d; int local;
    if (i < 163840) {
        const int seg = i >> 15; local = i & 32767;
        s = seg==0?Wq:seg==1?Wk:seg==2?Wv:seg==3?Wqp:Wkp;
        d = dst + (size_t)seg*262144;
    } else if (i < 196608) {
        const int j = i - 163840; const int seg = j >> 14; local = j & 16383;
        s = seg ? Wka : Wqa;
        d = dst + 1310720 + (size_t)seg*131072;
    } else {
        local = i - 196608;
        s = Wd; d = dst + 1572864;
    }
    f32x4 a = ((const f32x4*)s)[local*2];
    f32x4 b = ((const f32x4*)s)[local*2+1];
    u16x8 o = { f2bf(a[0]),f2bf(a[1]),f2bf(a[2]),f2bf(a[3]),
                f2bf(b[0]),f2bf(b[1]),f2bf(b[2]),f2bf(b[3]) };
    ((u16x8*)d)[local] = o;
}

// fw1 f32 [256][256] -> bf16 pre-swizzled [row][256] (XOR (row&7)<<4 on bytes)
__global__ __launch_bounds__(64) void prep_fw1(const float* __restrict__ fw1,
                                               u16* __restrict__ fw1b)
{
    const int row = blockIdx.x;
    const int c0  = threadIdx.x * 4;
    float4 v = *(const float4*)(fw1 + (size_t)row*256 + c0);
    u16x4 pk = { f2bf(v.x), f2bf(v.y), f2bf(v.z), f2bf(v.w) };
    *(u16x4*)((char*)fw1b + (size_t)row*512 + ((c0*2) ^ ((row&7)<<4))) = pk;
}

// ---------------------------------------------------------------------------
// 128x128 tile GEMM, BK=64, 4 waves, global_load_lds staging.
// Grid: 1D, XCD-banded raster.
// Per-ks fragment loads + launch_bounds(256,4): VGPR=64, LDS=32KB ->
// 4 blocks/CU (16 waves/CU) for barrier-latency hiding.
// OUTMODE 2: f32 out o0 = acc + b0 + resid
// OUTMODE 4: QKV router (N=1536)  OUTMODE 5: QP/KP  OUTMODE 6: attr
// ---------------------------------------------------------------------------
template<int OUTMODE, int BBF16>
__global__ __launch_bounds__(256,4) void gemm128(
    const u16* __restrict__ A, const void* __restrict__ Bv,
    void* __restrict__ o0, void* __restrict__ o1, void* __restrict__ o2,
    const float* __restrict__ b0, const float* __restrict__ b1,
    const float* __restrict__ b2, const float* __restrict__ resid,
    int N, int K)
{
    __shared__ char sA[16384];
    __shared__ char sB[16384];
    const int tid = threadIdx.x, lane = tid & 63, w = tid >> 6;
    const int wr = (w & 1) * 64, wc = (w >> 1) * 64;
    const int flat = blockIdx.x;
    const int xcd = flat & 7, bi2 = flat >> 3;
    const int n_i = bi2 >> 4, mIn = bi2 & 15;
    const int m0 = (xcd*16 + mIn)*128, n0 = n_i*128;

    f32x4 acc[4][4];
    #pragma unroll
    for (int mi = 0; mi < 4; mi++)
        #pragma unroll
        for (int ni = 0; ni < 4; ni++) acc[mi][ni] = (f32x4){0.f,0.f,0.f,0.f};

    for (int k0 = 0; k0 < K; k0 += 64) {
        __syncthreads();
        #pragma unroll
        for (int i = 0; i < 4; i++) {
            const int off = w*4096 + i*1024 + lane*16;
            const int r = off >> 7, c = off & 0x70;
            gload16(A + (size_t)(m0 + r)*K + k0 + ((c ^ ((r&7)<<4)) >> 1),
                    sA + w*4096 + i*1024);
        }
        if (BBF16) {
            const u16* B = (const u16*)Bv;
            #pragma unroll
            for (int i = 0; i < 4; i++) {
                const int off = w*4096 + i*1024 + lane*16;
                const int r = off >> 7, c = off & 0x70;
                gload16(B + (size_t)(n0 + r)*K + k0 + ((c ^ ((r&7)<<4)) >> 1),
                        sB + w*4096 + i*1024);
            }
        } else {
            const float* B = (const float*)Bv;
            const int r = tid >> 1, cseg = (tid & 1) * 32;
            const float* p = B + (size_t)(n0 + r)*K + k0 + cseg;
            alignas(16) u16 tmp[32];
            #pragma unroll
            for (int j = 0; j < 8; j++) {
                float4 fv = ((const float4*)p)[j];
                tmp[j*4+0]=f2bf(fv.x); tmp[j*4+1]=f2bf(fv.y);
                tmp[j*4+2]=f2bf(fv.z); tmp[j*4+3]=f2bf(fv.w);
            }
            const int rx = (r&7)<<4;
            #pragma unroll
            for (int j = 0; j < 4; j++)
                *(u16x8*)(sB + r*128 + ((cseg*2 + j*16) ^ rx)) = *(u16x8*)(tmp + j*8);
        }
        __syncthreads();
        #pragma unroll
        for (int ks = 0; ks < 2; ks++) {
            const int kb = ks*64 + (lane>>4)*16;
            bf16x8 af[4], bf[4];
            #pragma unroll
            for (int mi = 0; mi < 4; mi++) {
                const int r = wr + mi*16 + (lane&15);
                af[mi] = *(const bf16x8*)(sA + r*128 + (kb ^ ((r&7)<<4)));
            }
            #pragma unroll
            for (int ni = 0; ni < 4; ni++) {
                const int r = wc + ni*16 + (lane&15);
                bf[ni] = *(const bf16x8*)(sB + r*128 + (kb ^ ((r&7)<<4)));
            }
            #pragma unroll
            for (int mi = 0; mi < 4; mi++)
                #pragma unroll
                for (int ni = 0; ni < 4; ni++)
                    acc[mi][ni] = __builtin_amdgcn_mfma_f32_16x16x32_bf16(
                        af[mi], bf[ni], acc[mi][ni], 0,0,0);
        }
    }
    #pragma unroll
    for (int mi = 0; mi < 4; mi++) {
        const int rowb = m0 + wr + mi*16 + (lane>>4)*4;
        const int bi = rowb >> 8, s0 = rowb & 255;
        #pragma unroll
        for (int ni = 0; ni < 4; ni++) {
            const int gn = n0 + wc + ni*16 + (lane&15);
            if (OUTMODE == 2) {
                float* out = (float*)o0;
                const float bb = b0[gn];
                #pragma unroll
                for (int r = 0; r < 4; r++) {
                    size_t idx = (size_t)(rowb+r)*N + gn;
                    out[idx] = acc[mi][ni][r] + bb + resid[idx];
                }
            } else if (OUTMODE == 4) {
                const int seg = gn >> 9, o = gn & 511;
                const int hh = o >> 6, d = o & 63;
                const float bb = (seg==0?b0:seg==1?b1:b2)[o];
                const int bh = bi*8 + hh;
                if (seg < 2) {
                    char* outp = (char*)(seg ? o1 : o0);
                    #pragma unroll
                    for (int r = 0; r < 4; r++) {
                        const int s = s0 + r;
                        *(u16*)(outp + zrow(bh,s) + ((d*2) ^ ((s&7)<<4)))
                            = f2bf(acc[mi][ni][r] + bb);
                    }
                } else {
                    u16x4 pk;
                    #pragma unroll
                    for (int r = 0; r < 4; r++) pk[r] = f2bf(acc[mi][ni][r] + bb);
                    *(u16x4*)((char*)o2 + (size_t)bh*32768 + d*512
                                        + ((s0*2) ^ ((d&7)<<4))) = pk;
                }
            } else if (OUTMODE == 5) {
                const int seg = gn >> 9, o = gn & 511;
                const int hh = o >> 6, d = o & 63;
                const float bb = (seg ? b1 : b0)[o];
                const int bh = bi*8 + hh;
                char* outp = (char*)(seg ? o1 : o0);
                #pragma unroll
                for (int r = 0; r < 4; r++) {
                    const int s = s0 + r;
                    *(u16*)(outp + zrow(bh,s) + (((64+d)*2) ^ ((s&7)<<4)))
                        = f2bf(acc[mi][ni][r] + bb);
                }
            } else { // 6: attr
                const int qk = gn >> 9, fo = gn & 511;
                const int f = fo >> 8, o = fo & 255;
                const int hh = o >> 5, d = o & 31;
                const int cb = 128 + f*32;
                const float bb = (qk ? b1 : b0)[fo];
                const int bh = bi*8 + hh;
                char* outp = (char*)(qk ? o1 : o0);
                #pragma unroll
                for (int r = 0; r < 4; r++) {
                    const int s = s0 + r;
                    *(u16*)(outp + zrow(bh,s) + (((cb+d)*2) ^ ((s&7)<<4)))
                        = f2bf(acc[mi][ni][r] + bb);
                }
            }
        }
    }
}

// ---------------------------------------------------------------------------
// K34B: merged K' + energy, split 2 blocks per bh by SOURCE-PAIR.
//   sp0: local d 0..63 = item (gd 0..63),   64..95 = attr0 (gd 128..159)
//   sp1: local d 0..63 = pos  (gd 64..127), 64..95 = attr1 (gd 160..191)
// 512 threads (8 waves), ~78KB LDS -> 2 blocks/CU (barrier overlap).
// ---------------------------------------------------------------------------
#define K34B_QZ   53248
#define K34B_QZSZ 13312
#define K34B_SMEM (53248 + 2*13312)   /* 79872 */

__global__ __launch_bounds__(512,4) void k34b(
    const u16* __restrict__ QZ, const u16* __restrict__ KZ,
    const u16* __restrict__ fw1b, const float* __restrict__ fb1,
    const float* __restrict__ fw2, float* __restrict__ e)
{
    extern __shared__ char sm[];
    const int tid = threadIdx.x, lane = tid & 63, w = tid >> 6;   // w 0..7
    const int bh = blockIdx.x >> 1, sp = blockIdx.x & 1;
    const int l15 = lane & 15, lq = lane >> 4;
    const int base0 = sp ? 64 : 0;      // gd base for local d 0..63
    const int base1 = sp ? 160 : 128;   // gd base for local d 64..95

    // stage one 64-row QZ tile (our 96 d cols) into R1 buf: 832 16B chunks
    auto stage_qz = [&](int qt4, int buf) {
        char* dst = sm + K34B_QZ + buf*K34B_QZSZ;
        {
            const int li = w*64 + lane;
            const int q = li / 13, c = li - q*13;
            const int cc = (c == 12) ? 0 : c;        // pad chunk: dup-load c0
            const int ld = cc*8;
            const int gd = (ld < 64) ? base0 + ld : base1 + (ld - 64);
            gload16((const char*)QZ + zrow(bh, qt4*64 + q)
                        + ((gd*2) ^ ((q&7)<<4)),
                    dst + w*1024);
        }
        if (w < 5) {
            const int li = 512 + w*64 + lane;
            const int q = li / 13, c = li - q*13;
            const int cc = (c == 12) ? 0 : c;
            const int ld = cc*8;
            const int gd = (ld < 64) ? base0 + ld : base1 + (ld - 64);
            gload16((const char*)QZ + zrow(bh, qt4*64 + q)
                        + ((gd*2) ^ ((q&7)<<4)),
                    dst + 8192 + w*1024);
        }
    };

    // ---- prefetch QZ tile 0 (async), then stage KZT-half [96 d][512B swz]
    stage_qz(0, 0);
    {
        const int spair = tid & 127, dg = tid >> 7;   // 128 s-pairs x 4 d-grps
        const int s0 = spair*2;
        const char* r0 = (const char*)KZ + zrow(bh, s0);
        const char* r1 = (const char*)KZ + zrow(bh, s0+1);
        const int sw0 = (s0&7)<<4, sw1 = ((s0+1)&7)<<4;
        #pragma unroll
        for (int m = 0; m < 3; m++) {
            const int ld0 = dg*24 + m*8;
            const int gd = (ld0 < 64) ? base0 + ld0 : base1 + (ld0 - 64);
            u16x8 v0 = *(const u16x8*)(r0 + ((gd*2) ^ sw0));
            u16x8 v1 = *(const u16x8*)(r1 + ((gd*2) ^ sw1));
            #pragma unroll
            for (int ee = 0; ee < 8; ee++) {
                const int d = ld0 + ee;
                *(u32*)(sm + d*512 + ((s0*2) ^ ((d&7)<<4)))
                    = (u32)v0[ee] | ((u32)v1[ee] << 16);
            }
        }
    }
    __syncthreads();

    // ---- phase 1: K'-half. wave=(jb, dh): j rows jb*64..+63, d cols dh*48..+47
    const int jb = w & 3, dh = w >> 2;
    f32x4 kacc[4][3];
    #pragma unroll
    for (int js = 0; js < 4; js++)
        #pragma unroll
        for (int ni = 0; ni < 3; ni++) kacc[js][ni] = (f32x4){0.f,0.f,0.f,0.f};
    #pragma unroll
    for (int ks = 0; ks < 8; ks++) {
        const int kb = ks*64 + lq*16;
        bf16x8 a[4];
        #pragma unroll
        for (int js = 0; js < 4; js++) {
            const int ar = jb*64 + js*16 + l15;
            a[js] = *(const bf16x8*)((const char*)fw1b + (size_t)ar*512
                                     + (kb ^ ((l15&7)<<4)));
        }
        #pragma unroll
        for (int ni = 0; ni < 3; ni++) {
            const int dr = dh*48 + ni*16 + l15;
            bf16x8 b = *(const bf16x8*)(sm + dr*512 + (kb ^ ((dr&7)<<4)));
            #pragma unroll
            for (int js = 0; js < 4; js++)
                kacc[js][ni] = __builtin_amdgcn_mfma_f32_16x16x32_bf16(
                    a[js], b, kacc[js][ni], 0,0,0);
        }
    }
    __syncthreads();   // all KZT reads done; KP overlays R0

    // ---- KP write: [256 j][pitch 208] bf16, no swizzle (208 spreads banks)
    #pragma unroll
    for (int js = 0; js < 4; js++)
        #pragma unroll
        for (int ni = 0; ni < 3; ni++) {
            const int d = dh*48 + ni*16 + l15;
            #pragma unroll
            for (int r = 0; r < 4; r++) {
                const int j = jb*64 + js*16 + lq*4 + r;
                *(u16*)(sm + j*208 + d*2) = f2bf(kacc[js][ni][r]);
            }
        }
    __syncthreads();

    // ---- af2: wave=(jb, qh) owns same 64 j rows, full 96 d (3 ks of 32)
    const int qh = w >> 2;
    bf16x8 af2[4][3];
    #pragma unroll
    for (int js = 0; js < 4; js++) {
        const int ar = jb*64 + js*16 + l15;
        #pragma unroll
        for (int ks = 0; ks < 3; ks++)
            af2[js][ks] = *(const bf16x8*)(sm + ar*208 + ks*64 + lq*16);
    }
    float f1v[4][4], f2v[4][4];
    #pragma unroll
    for (int js = 0; js < 4; js++)
        #pragma unroll
        for (int r = 0; r < 4; r++) {
            const int j = jb*64 + js*16 + lq*4 + r;
            f1v[js][r] = fb1[j]; f2v[js][r] = fw2[j];
        }

    // ---- phase 2: qt loop, 1 barrier/iter; E slabs [4 jb][2 sl][256 q] f32
    for (int qt = 0; qt < 4; qt++) {
        __syncthreads();   // drains stage(qt); buf[(qt+1)&1] free; af2/KP done
        if (qt < 3) stage_qz(qt+1, (qt+1)&1);
        const char* qb = sm + K34B_QZ + (qt&1)*K34B_QZSZ;
        #pragma unroll
        for (int qs = 0; qs < 2; qs++) {
            const int qoff = (qh*32 + qs*16 + l15)*208 + lq*16;
            f32x4 acc[4];
            // sl = 0: ks 0,1 (64-d source)
            #pragma unroll
            for (int js = 0; js < 4; js++) acc[js] = (f32x4){0.f,0.f,0.f,0.f};
            #pragma unroll
            for (int kk = 0; kk < 2; kk++) {
                bf16x8 b = *(const bf16x8*)(qb + qoff + kk*64);
                #pragma unroll
                for (int js = 0; js < 4; js++)
                    acc[js] = __builtin_amdgcn_mfma_f32_16x16x32_bf16(
                        af2[js][kk], b, acc[js], 0,0,0);
            }
            {
                float ep = 0.f;
                #pragma unroll
                for (int js = 0; js < 4; js++)
                    #pragma unroll
                    for (int r = 0; r < 4; r++)
                        ep += fmaxf(acc[js][r] + f1v[js][r], 0.f) * f2v[js][r];
                ep += __shfl_xor(ep, 16);
                ep += __shfl_xor(ep, 32);
                if (lane < 16)
                    ((float*)sm)[(jb*2 + 0)*256 + qt*64 + qh*32 + qs*16 + lane] = ep;
            }
            // sl = 1: ks 2 (32-d source)
            #pragma unroll
            for (int js = 0; js < 4; js++) acc[js] = (f32x4){0.f,0.f,0.f,0.f};
            {
                bf16x8 b = *(const bf16x8*)(qb + qoff + 128);
                #pragma unroll
                for (int js = 0; js < 4; js++)
                    acc[js] = __builtin_amdgcn_mfma_f32_16x16x32_bf16(
                        af2[js][2], b, acc[js], 0,0,0);
            }
            {
                float ep = 0.f;
                #pragma unroll
                for (int js = 0; js < 4; js++)
                    #pragma unroll
                    for (int r = 0; r < 4; r++)
                        ep += fmaxf(acc[js][r] + f1v[js][r], 0.f) * f2v[js][r];
                ep += __shfl_xor(ep, 16);
                ep += __shfl_xor(ep, 32);
                if (lane < 16)
                    ((float*)sm)[(jb*2 + 1)*256 + qt*64 + qh*32 + qs*16 + lane] = ep;
            }
        }
    }
    __syncthreads();
    {   // final reduce over 4 jb slabs; e src order: {item,pos,attr0,attr1}
        const int q = tid & 255, sl = tid >> 8;
        const float* el = (const float*)sm;
        float s = 0.f;
        #pragma unroll
        for (int j2 = 0; j2 < 4; j2++) s += el[(j2*2 + sl)*256 + q];
        const int gsrc = sl ? (2 + sp) : sp;
        e[((size_t)bh*256 + q)*4 + gsrc] = s;
    }
}

// ---------------------------------------------------------------------------
// K5B: gates -> mixed = (g.QZ) @ KZ^T -> row softmax -> PV -> ctx
// 52KB LDS -> 3 blocks/CU (12 waves/CU).
// ---------------------------------------------------------------------------
#define K5_KZ 24576
#define K5_VT 36864
#define K5_SMEM 53248

__global__ __launch_bounds__(256,3) void k5b(
    const u16* __restrict__ QZ, const u16* __restrict__ KZ,
    const u16* __restrict__ VT, const float* __restrict__ e,
    u16* __restrict__ ctx)
{
    extern __shared__ char sm[];
    const int tid = threadIdx.x, lane = tid & 63, w = tid >> 6;
    const int flat = blockIdx.x;
    const int xcd = flat & 7, idx = flat >> 3;   // idx < 256
    const int qt = idx & 3;
    const int bh = (idx >> 2) * 8 + xcd;
    const int q0 = qt*64;
    const int b = bh >> 3, h = bh & 7;
    const int kq16 = (lane>>4)*16;
    const char* QZc = (const char*)QZ + zrow(bh, q0);
    const char* KZc = (const char*)KZ + zrow(bh, 0);
    const char* VTc = (const char*)VT + (size_t)bh*32768;

    // initial staging: QZ 24KB + KZ chunk0 12KB + VT chunk0 8KB (verbatim)
    #pragma unroll
    for (int i = 0; i < 6; i++)
        gload16(QZc + i*4096 + tid*16, sm + i*4096 + tid*16);
    #pragma unroll
    for (int i = 0; i < 3; i++)
        gload16(KZc + i*4096 + tid*16, sm + K5_KZ + i*4096 + tid*16);
    #pragma unroll
    for (int i = 0; i < 2; i++)
        gload16(VTc + i*4096 + tid*16, sm + K5_VT + i*4096 + tid*16);
    __syncthreads();

    const int qrow = w*16 + (lane&15);
    float ga[4];
    {
        f32x4 ev = *(const f32x4*)(e + ((size_t)bh*256 + q0 + qrow)*4);
        float em = fmaxf(fmaxf(ev[0],ev[1]), fmaxf(ev[2],ev[3]));
        float s = 0.f;
        #pragma unroll
        for (int j = 0; j < 4; j++) { ga[j] = __expf(ev[j]-em); s += ga[j]; }
        const float gi = 1.f / s;
        #pragma unroll
        for (int j = 0; j < 4; j++) ga[j] *= gi;
    }
    const int asw = ((lane&15)&7) << 4;
    bf16x8 aF[6];
    #pragma unroll
    for (int ks = 0; ks < 6; ks++) {
        const int sidx = (ks<2)?0:(ks<4)?1:(ks<5)?2:3;
        u16x8 v = *(const u16x8*)(sm + qrow*384 + ((ks*64 + kq16) ^ asw));
        const float gg = ga[sidx];
        u16x8 pk;
        #pragma unroll
        for (int j = 0; j < 8; j++) pk[j] = f2bf(bf2f(v[j]) * gg);
        aF[ks] = __builtin_bit_cast(bf16x8, pk);
    }

    // ---- QK^T over 8 chunks of 32 k-rows, reg-prefetch swap (T14)
    f32x4 macc[16];
    #pragma unroll
    for (int t = 0; t < 16; t++) macc[t] = (f32x4){0.f,0.f,0.f,0.f};
    u16x8 kreg[3];
    #pragma unroll
    for (int kt = 0; kt < 8; kt++) {
        if (kt < 7) {
            #pragma unroll
            for (int j = 0; j < 3; j++)
                kreg[j] = *(const u16x8*)(KZc + (size_t)(kt+1)*12288
                                          + (tid + j*256)*16);
        }
        #pragma unroll
        for (int n2 = 0; n2 < 2; n2++) {
            const int kr = n2*16 + (lane&15);
            const int ksw = (kr&7)<<4;
            #pragma unroll
            for (int ks = 0; ks < 6; ks++) {
                bf16x8 bb = *(const bf16x8*)(sm + K5_KZ + kr*384
                                             + ((ks*64 + kq16) ^ ksw));
                macc[kt*2+n2] = __builtin_amdgcn_mfma_f32_16x16x32_bf16(
                    aF[ks], bb, macc[kt*2+n2], 0,0,0);
            }
        }
        if (kt < 7) {
            __syncthreads();
            #pragma unroll
            for (int j = 0; j < 3; j++)
                *(u16x8*)(sm + K5_KZ + (tid + j*256)*16) = kreg[j];
            __syncthreads();
        }
    }
    __syncthreads();   // all waves done with KZ/QZ before probs overlay

    // ---- softmax + probs write [64 q][512B swz] overlaying [0,32768)
    #pragma unroll
    for (int rr = 0; rr < 4; rr++) {
        float mx = -3.4e38f;
        #pragma unroll
        for (int t = 0; t < 16; t++) mx = fmaxf(mx, macc[t][rr]);
        #pragma unroll
        for (int msk = 1; msk < 16; msk <<= 1) mx = fmaxf(mx, __shfl_xor(mx, msk));
        float s = 0.f;
        #pragma unroll
        for (int t = 0; t < 16; t++) {
            float pv = __expf((macc[t][rr] - mx) * 0.125f);
            macc[t][rr] = pv; s += pv;
        }
        #pragma unroll
        for (int msk = 1; msk < 16; msk <<= 1) s += __shfl_xor(s, msk);
        const float inv = 1.f / s;
        const int orow = w*16 + (lane>>4)*4 + rr;
        const int osw = (orow&7)<<4;
        #pragma unroll
        for (int t = 0; t < 16; t++) {
            const int col = t*16 + (lane&15);
            *(u16*)(sm + orow*512 + ((col*2) ^ osw)) = f2bf(macc[t][rr]*inv);
        }
    }
    __syncthreads();

    // ---- PV: probs a-frags in regs; VT d-tiles double-buffered
    bf16x8 a[8];
    const int prow = w*16 + (lane&15);
    const int psw = ((lane&15)&7)<<4;
    #pragma unroll
    for (int ks = 0; ks < 8; ks++)
        a[ks] = *(const bf16x8*)(sm + prow*512 + ((ks*64 + kq16) ^ psw));

    const int orow = w*16 + (lane>>4)*4;
    #pragma unroll
    for (int n = 0; n < 4; n++) {
        if (n < 3) {   // prefetch next VT d-tile into other buf
            #pragma unroll
            for (int i = 0; i < 2; i++)
                gload16(VTc + (size_t)(n+1)*8192 + i*4096 + tid*16,
                        sm + K5_VT + ((n+1)&1)*8192 + i*4096 + tid*16);
        }
        f32x4 pacc = (f32x4){0.f,0.f,0.f,0.f};
        const char* vb = sm + K5_VT + (n&1)*8192;
        const int dl = lane & 15;
        const int vsw = (dl&7)<<4;
        #pragma unroll
        for (int ks = 0; ks < 8; ks++) {
            bf16x8 bb = *(const bf16x8*)(vb + dl*512 + ((ks*64 + kq16) ^ vsw));
            pacc = __builtin_amdgcn_mfma_f32_16x16x32_bf16(a[ks], bb, pacc, 0,0,0);
        }
        {
            const int d = n*16 + dl;
            #pragma unroll
            for (int r = 0; r < 4; r++) {
                const size_t grow = (size_t)b*256 + q0 + orow + r;
                ctx[grow*512 + h*64 + d] = f2bf(pacc[r]);
            }
        }
        if (n < 3) __syncthreads();   // drain prefetch; free read buf
    }
}

// ---------------------------------------------------------------------------
__global__ __launch_bounds__(256) void ln_k(float* __restrict__ x,
    const float* __restrict__ gamma, const float* __restrict__ beta)
{
    const int row = blockIdx.x*4 + (threadIdx.x >> 6);
    const int l = threadIdx.x & 63;
    float* p = x + (size_t)row*HDIM;
    f32x4 v0 = *(const f32x4*)(p + l*4);
    f32x4 v1 = *(const f32x4*)(p + 256 + l*4);
    float s = v0[0]+v0[1]+v0[2]+v0[3] + v1[0]+v1[1]+v1[2]+v1[3];
    #pragma unroll
    for (int msk = 1; msk < 64; msk <<= 1) s += __shfl_xor(s, msk);
    const float mu = s * (1.f/512.f);
    float vs = 0.f;
    #pragma unroll
    for (int j = 0; j < 4; j++) {
        float d0 = v0[j]-mu, d1 = v1[j]-mu;
        vs += d0*d0 + d1*d1;
    }
    #pragma unroll
    for (int msk = 1; msk < 64; msk <<= 1) vs += __shfl_xor(vs, msk);
    const float inv = 1.f / sqrtf(vs * (1.f/512.f) + 1e-12f);
    f32x4 o0, o1;
    #pragma unroll
    for (int j = 0; j < 4; j++) {
        o0[j] = gamma[l*4+j]     * (v0[j]-mu) * inv + beta[l*4+j];
        o1[j] = gamma[256+l*4+j] * (v1[j]-mu) * inv + beta[256+l*4+j];
    }
    *(f32x4*)(p + l*4) = o0;
    *(f32x4*)(p + 256 + l*4) = o1;
}

// ---------------------------------------------------------------------------
extern "C" void kernel_launch(void* const* d_in, const int* in_sizes, int n_in,
                              void* d_out, int out_size, void* d_ws, size_t ws_size,
                              hipStream_t stream)
{
    const float* input = (const float*)d_in[0];
    const float* attrt = (const float*)d_in[1];
    const float* pose  = (const float*)d_in[2];
    const float* Wq  = (const float*)d_in[3];  const float* bq  = (const float*)d_in[4];
    const float* Wk  = (const float*)d_in[5];  const float* bk  = (const float*)d_in[6];
    const float* Wv  = (const float*)d_in[7];  const float* bv  = (const float*)d_in[8];
    const float* Wqp = (const float*)d_in[9];  const float* bqp = (const float*)d_in[10];
    const float* Wkp = (const float*)d_in[11]; const float* bkp = (const float*)d_in[12];
    const float* Wqa = (const float*)d_in[13]; const float* bqa = (const float*)d_in[14];
    const float* Wka = (const float*)d_in[15]; const float* bka = (const float*)d_in[16];
    const float* fw1 = (const float*)d_in[17]; const float* fb1 = (const float*)d_in[18];
    const float* fw2 = (const float*)d_in[19]; /* fb2 cancels in softmax */
    const float* Wd  = (const float*)d_in[21]; const float* bd  = (const float*)d_in[22];
    const float* gamma = (const float*)d_in[23]; const float* beta = (const float*)d_in[24];

    char* ws = (char*)d_ws;
    u16*   wsQZ  = (u16*)(ws);                      // 50,331,648 B
    u16*   wsKZ  = (u16*)(ws + 50331648);           // 50,331,648 B
    u16*   wsTmp = (u16*)(ws + 100663296);          // 16,777,216 B (inB/poseB -> ctx)
    float* wsE   = (float*)(ws + 117440512);        //  2,097,152 B
    u16*   fw1b  = (u16*)(ws + 119537664);          //    131,072 B
    u16*   dW    = (u16*)(ws + 119668736);          //  3,670,016 B (incl Wd)
    u16*   wsVT  = (u16*)d_out;                     // 16,777,216 B (dead before final GEMM)

    dim3 blk(256);

    cvtW_k<<<dim3(896), blk, 0, stream>>>(Wq, Wk, Wv, Wqp, Wkp, Wqa, Wka, Wd, dW);
    prep_fw1<<<dim3(256), dim3(64), 0, stream>>>(fw1, fw1b);

    cvt_k<<<dim3(2048), blk, 0, stream>>>(attrt, wsTmp, 524288);
    gemm128<6,1><<<dim3(1024), blk, 0, stream>>>(wsTmp, dW + 1310720,
        wsQZ, wsKZ, nullptr, bqa, bka, nullptr, nullptr, 1024, 256);
    cvt_k<<<dim3(2048), blk, 0, stream>>>(input, wsTmp, 1048576);
    gemm128<4,1><<<dim3(1536), blk, 0, stream>>>(wsTmp, dW,
        wsQZ, wsKZ, wsVT, bq, bk, bv, nullptr, 1536, 512);
    cvt_k<<<dim3(2048), blk, 0, stream>>>(pose, wsTmp, 1048576);
    gemm128<5,1><<<dim3(1024), blk, 0, stream>>>(wsTmp, dW + 786432,
        wsQZ, wsKZ, nullptr, bqp, bkp, nullptr, nullptr, 1024, 512);

    // merged K' + energy: 2 blocks per bh (source-pair split), 2 blocks/CU
    hipFuncSetAttribute(reinterpret_cast<const void*>(k34b),
                        hipFuncAttributeMaxDynamicSharedMemorySize, K34B_SMEM);
    k34b<<<dim3(NBH*2), dim3(512), K34B_SMEM, stream>>>(wsQZ, wsKZ, fw1b, fb1, fw2, wsE);

    hipFuncSetAttribute(reinterpret_cast<const void*>(k5b),
                        hipFuncAttributeMaxDynamicSharedMemorySize, K5_SMEM);
    k5b<<<dim3(2048), blk, K5_SMEM, stream>>>(wsQZ, wsKZ, wsVT, wsE, wsTmp);

    gemm128<2,1><<<dim3(512), blk, 0, stream>>>(wsTmp, dW + 1572864,
        d_out, nullptr, nullptr, bd, nullptr, nullptr, input, 512, 512);
    ln_k<<<dim3(BS/4), blk, 0, stream>>>((float*)d_out, gamma, beta);
}

// Round 9
// 232.892 us; speedup vs baseline: 1.1613x; 1.0083x over previous
//
#include <hip/hip_runtime.h>

typedef unsigned short u16;
typedef unsigned int   u32;
typedef __bf16 bf16x8 __attribute__((ext_vector_type(8)));
typedef float  f32x4  __attribute__((ext_vector_type(4)));
typedef u16    u16x4  __attribute__((ext_vector_type(4)));
typedef u16    u16x8  __attribute__((ext_vector_type(8)));

#define BB 64
#define SS 256
#define HDIM 512
#define NHEAD 8
#define BS (BB*SS)            /* 16384 */
#define NBH 512

__device__ __forceinline__ u16 f2bf(float f){
    u32 u = __builtin_bit_cast(u32, f);
    u32 r = u + 0x7FFFu + ((u>>16)&1u);
    return (u16)(r>>16);
}
__device__ __forceinline__ float bf2f(u16 u){
    return __builtin_bit_cast(float, (u32)u<<16);
}
__device__ __forceinline__ void gload16(const void* g, void* l){
    __builtin_amdgcn_global_load_lds(
        (const __attribute__((address_space(1))) void*)g,
        (__attribute__((address_space(3))) void*)l, 16, 0, 0);
}

// QZ/KZ row layout: [bh][s] rows of 384B; elem d at byte ((d*2) ^ ((s&7)<<4))
__device__ __forceinline__ size_t zrow(int bh, int s){
    return ((size_t)bh*256 + s)*384;
}

// ---------------------------------------------------------------------------
// f32 -> bf16 grid-stride converter (vec8)
// ---------------------------------------------------------------------------
__global__ __launch_bounds__(256) void cvt_k(const float* __restrict__ s,
                                             u16* __restrict__ d, int n8)
{
    int i = blockIdx.x*256 + threadIdx.x;
    const int stride = gridDim.x*256;
    for (; i < n8; i += stride) {
        f32x4 a = ((const f32x4*)s)[i*2];
        f32x4 b = ((const f32x4*)s)[i*2+1];
        u16x8 o = { f2bf(a[0]),f2bf(a[1]),f2bf(a[2]),f2bf(a[3]),
                    f2bf(b[0]),f2bf(b[1]),f2bf(b[2]),f2bf(b[3]) };
        ((u16x8*)d)[i] = o;
    }
}

// weights -> bf16 arena (u16 offsets): Wq@0 Wk@262144 Wv@524288 Wqp@786432
// Wkp@1048576 Wqa@1310720 Wka@1441792 Wd@1572864
__global__ __launch_bounds__(256) void cvtW_k(
    const float* __restrict__ Wq,  const float* __restrict__ Wk,
    const float* __restrict__ Wv,  const float* __restrict__ Wqp,
    const float* __restrict__ Wkp, const float* __restrict__ Wqa,
    const float* __restrict__ Wka, const float* __restrict__ Wd,
    u16* __restrict__ dst)
{
    const int i = blockIdx.x*256 + threadIdx.x;   // 229376 threads
    const float* s; u16* d; int local;
    if (i < 163840) {
        const int seg = i >> 15; local = i & 32767;
        s = seg==0?Wq:seg==1?Wk:seg==2?Wv:seg==3?Wqp:Wkp;
        d = dst + (size_t)seg*262144;
    } else if (i < 196608) {
        const int j = i - 163840; const int seg = j >> 14; local = j & 16383;
        s = seg ? Wka : Wqa;
        d = dst + 1310720 + (size_t)seg*131072;
    } else {
        local = i - 196608;
        s = Wd; d = dst + 1572864;
    }
    f32x4 a = ((const f32x4*)s)[local*2];
    f32x4 b = ((const f32x4*)s)[local*2+1];
    u16x8 o = { f2bf(a[0]),f2bf(a[1]),f2bf(a[2]),f2bf(a[3]),
                f2bf(b[0]),f2bf(b[1]),f2bf(b[2]),f2bf(b[3]) };
    ((u16x8*)d)[local] = o;
}

// fw1 f32 [256][256] -> FRAGMENT-ORDERED bf16: for (jt=j>>4, ks=k>>5), the
// 64 lanes' 16B a-frags stored contiguously at ((jt*8+ks)*64 + lq*16+l15)*16,
// lq=(k>>3)&3, l15=j&15. A wave's phase-1 A-load = one coalesced 1KB burst.
__global__ __launch_bounds__(64) void prep_fw1(const float* __restrict__ fw1,
                                               u16* __restrict__ fw1f)
{
    const int j = blockIdx.x*2 + (threadIdx.x >> 5);
    const int t = threadIdx.x & 31;       // 8-elem k chunk index
    const int k0 = t*8;
    f32x4 a = *(const f32x4*)(fw1 + (size_t)j*256 + k0);
    f32x4 b = *(const f32x4*)(fw1 + (size_t)j*256 + k0 + 4);
    u16x8 o = { f2bf(a[0]),f2bf(a[1]),f2bf(a[2]),f2bf(a[3]),
                f2bf(b[0]),f2bf(b[1]),f2bf(b[2]),f2bf(b[3]) };
    const int jt = j >> 4, ks = t >> 2, lq = t & 3;
    ((u16x8*)fw1f)[(jt*8 + ks)*64 + lq*16 + (j & 15)] = o;
}

// ---------------------------------------------------------------------------
// 128x128 tile GEMM, BK=64, 4 waves, global_load_lds staging.
// Grid: 1D, XCD-banded raster. launch_bounds(256,4): 4 blocks/CU.
// OUTMODE 2: f32 out o0 = acc + b0 + resid
// OUTMODE 4: QKV router (N=1536)  OUTMODE 5: QP/KP  OUTMODE 6: attr
// ---------------------------------------------------------------------------
template<int OUTMODE, int BBF16>
__global__ __launch_bounds__(256,4) void gemm128(
    const u16* __restrict__ A, const void* __restrict__ Bv,
    void* __restrict__ o0, void* __restrict__ o1, void* __restrict__ o2,
    const float* __restrict__ b0, const float* __restrict__ b1,
    const float* __restrict__ b2, const float* __restrict__ resid,
    int N, int K)
{
    __shared__ char sA[16384];
    __shared__ char sB[16384];
    const int tid = threadIdx.x, lane = tid & 63, w = tid >> 6;
    const int wr = (w & 1) * 64, wc = (w >> 1) * 64;
    const int flat = blockIdx.x;
    const int xcd = flat & 7, bi2 = flat >> 3;
    const int n_i = bi2 >> 4, mIn = bi2 & 15;
    const int m0 = (xcd*16 + mIn)*128, n0 = n_i*128;

    f32x4 acc[4][4];
    #pragma unroll
    for (int mi = 0; mi < 4; mi++)
        #pragma unroll
        for (int ni = 0; ni < 4; ni++) acc[mi][ni] = (f32x4){0.f,0.f,0.f,0.f};

    for (int k0 = 0; k0 < K; k0 += 64) {
        __syncthreads();
        #pragma unroll
        for (int i = 0; i < 4; i++) {
            const int off = w*4096 + i*1024 + lane*16;
            const int r = off >> 7, c = off & 0x70;
            gload16(A + (size_t)(m0 + r)*K + k0 + ((c ^ ((r&7)<<4)) >> 1),
                    sA + w*4096 + i*1024);
        }
        if (BBF16) {
            const u16* B = (const u16*)Bv;
            #pragma unroll
            for (int i = 0; i < 4; i++) {
                const int off = w*4096 + i*1024 + lane*16;
                const int r = off >> 7, c = off & 0x70;
                gload16(B + (size_t)(n0 + r)*K + k0 + ((c ^ ((r&7)<<4)) >> 1),
                        sB + w*4096 + i*1024);
            }
        } else {
            const float* B = (const float*)Bv;
            const int r = tid >> 1, cseg = (tid & 1) * 32;
            const float* p = B + (size_t)(n0 + r)*K + k0 + cseg;
            alignas(16) u16 tmp[32];
            #pragma unroll
            for (int j = 0; j < 8; j++) {
                float4 fv = ((const float4*)p)[j];
                tmp[j*4+0]=f2bf(fv.x); tmp[j*4+1]=f2bf(fv.y);
                tmp[j*4+2]=f2bf(fv.z); tmp[j*4+3]=f2bf(fv.w);
            }
            const int rx = (r&7)<<4;
            #pragma unroll
            for (int j = 0; j < 4; j++)
                *(u16x8*)(sB + r*128 + ((cseg*2 + j*16) ^ rx)) = *(u16x8*)(tmp + j*8);
        }
        __syncthreads();
        #pragma unroll
        for (int ks = 0; ks < 2; ks++) {
            const int kb = ks*64 + (lane>>4)*16;
            bf16x8 af[4], bf[4];
            #pragma unroll
            for (int mi = 0; mi < 4; mi++) {
                const int r = wr + mi*16 + (lane&15);
                af[mi] = *(const bf16x8*)(sA + r*128 + (kb ^ ((r&7)<<4)));
            }
            #pragma unroll
            for (int ni = 0; ni < 4; ni++) {
                const int r = wc + ni*16 + (lane&15);
                bf[ni] = *(const bf16x8*)(sB + r*128 + (kb ^ ((r&7)<<4)));
            }
            #pragma unroll
            for (int mi = 0; mi < 4; mi++)
                #pragma unroll
                for (int ni = 0; ni < 4; ni++)
                    acc[mi][ni] = __builtin_amdgcn_mfma_f32_16x16x32_bf16(
                        af[mi], bf[ni], acc[mi][ni], 0,0,0);
        }
    }
    #pragma unroll
    for (int mi = 0; mi < 4; mi++) {
        const int rowb = m0 + wr + mi*16 + (lane>>4)*4;
        const int bi = rowb >> 8, s0 = rowb & 255;
        #pragma unroll
        for (int ni = 0; ni < 4; ni++) {
            const int gn = n0 + wc + ni*16 + (lane&15);
            if (OUTMODE == 2) {
                float* out = (float*)o0;
                const float bb = b0[gn];
                #pragma unroll
                for (int r = 0; r < 4; r++) {
                    size_t idx = (size_t)(rowb+r)*N + gn;
                    out[idx] = acc[mi][ni][r] + bb + resid[idx];
                }
            } else if (OUTMODE == 4) {
                const int seg = gn >> 9, o = gn & 511;
                const int hh = o >> 6, d = o & 63;
                const float bb = (seg==0?b0:seg==1?b1:b2)[o];
                const int bh = bi*8 + hh;
                if (seg < 2) {
                    char* outp = (char*)(seg ? o1 : o0);
                    #pragma unroll
                    for (int r = 0; r < 4; r++) {
                        const int s = s0 + r;
                        *(u16*)(outp + zrow(bh,s) + ((d*2) ^ ((s&7)<<4)))
                            = f2bf(acc[mi][ni][r] + bb);
                    }
                } else {
                    u16x4 pk;
                    #pragma unroll
                    for (int r = 0; r < 4; r++) pk[r] = f2bf(acc[mi][ni][r] + bb);
                    *(u16x4*)((char*)o2 + (size_t)bh*32768 + d*512
                                        + ((s0*2) ^ ((d&7)<<4))) = pk;
                }
            } else if (OUTMODE == 5) {
                const int seg = gn >> 9, o = gn & 511;
                const int hh = o >> 6, d = o & 63;
                const float bb = (seg ? b1 : b0)[o];
                const int bh = bi*8 + hh;
                char* outp = (char*)(seg ? o1 : o0);
                #pragma unroll
                for (int r = 0; r < 4; r++) {
                    const int s = s0 + r;
                    *(u16*)(outp + zrow(bh,s) + (((64+d)*2) ^ ((s&7)<<4)))
                        = f2bf(acc[mi][ni][r] + bb);
                }
            } else { // 6: attr
                const int qk = gn >> 9, fo = gn & 511;
                const int f = fo >> 8, o = fo & 255;
                const int hh = o >> 5, d = o & 31;
                const int cb = 128 + f*32;
                const float bb = (qk ? b1 : b0)[fo];
                const int bh = bi*8 + hh;
                char* outp = (char*)(qk ? o1 : o0);
                #pragma unroll
                for (int r = 0; r < 4; r++) {
                    const int s = s0 + r;
                    *(u16*)(outp + zrow(bh,s) + (((cb+d)*2) ^ ((s&7)<<4)))
                        = f2bf(acc[mi][ni][r] + bb);
                }
            }
        }
    }
}

// ---------------------------------------------------------------------------
// K34B: merged K' + energy, split 2 blocks per bh by SOURCE-PAIR.
//   sp0: local d 0..63 = item (gd 0..63),   64..95 = attr0 (gd 128..159)
//   sp1: local d 0..63 = pos  (gd 64..127), 64..95 = attr1 (gd 160..191)
// 512 threads (8 waves), ~78KB LDS -> 2 blocks/CU (barrier overlap).
// Phase-1 A-frags from FRAGMENT-ORDERED fw1f: 1KB coalesced bursts.
// ---------------------------------------------------------------------------
#define K34B_QZ   53248
#define K34B_QZSZ 13312
#define K34B_SMEM (53248 + 2*13312)   /* 79872 */

__global__ __launch_bounds__(512,4) void k34b(
    const u16* __restrict__ QZ, const u16* __restrict__ KZ,
    const u16* __restrict__ fw1f, const float* __restrict__ fb1,
    const float* __restrict__ fw2, float* __restrict__ e)
{
    extern __shared__ char sm[];
    const int tid = threadIdx.x, lane = tid & 63, w = tid >> 6;   // w 0..7
    const int bh = blockIdx.x >> 1, sp = blockIdx.x & 1;
    const int l15 = lane & 15, lq = lane >> 4;
    const int base0 = sp ? 64 : 0;      // gd base for local d 0..63
    const int base1 = sp ? 160 : 128;   // gd base for local d 64..95

    // stage one 64-row QZ tile (our 96 d cols) into R1 buf: 832 16B chunks
    auto stage_qz = [&](int qt4, int buf) {
        char* dst = sm + K34B_QZ + buf*K34B_QZSZ;
        {
            const int li = w*64 + lane;
            const int q = li / 13, c = li - q*13;
            const int cc = (c == 12) ? 0 : c;        // pad chunk: dup-load c0
            const int ld = cc*8;
            const int gd = (ld < 64) ? base0 + ld : base1 + (ld - 64);
            gload16((const char*)QZ + zrow(bh, qt4*64 + q)
                        + ((gd*2) ^ ((q&7)<<4)),
                    dst + w*1024);
        }
        if (w < 5) {
            const int li = 512 + w*64 + lane;
            const int q = li / 13, c = li - q*13;
            const int cc = (c == 12) ? 0 : c;
            const int ld = cc*8;
            const int gd = (ld < 64) ? base0 + ld : base1 + (ld - 64);
            gload16((const char*)QZ + zrow(bh, qt4*64 + q)
                        + ((gd*2) ^ ((q&7)<<4)),
                    dst + 8192 + w*1024);
        }
    };

    // ---- prefetch QZ tile 0 (async), then stage KZT-half [96 d][512B swz]
    stage_qz(0, 0);
    {
        const int spair = tid & 127, dg = tid >> 7;   // 128 s-pairs x 4 d-grps
        const int s0 = spair*2;
        const char* r0 = (const char*)KZ + zrow(bh, s0);
        const char* r1 = (const char*)KZ + zrow(bh, s0+1);
        const int sw0 = (s0&7)<<4, sw1 = ((s0+1)&7)<<4;
        #pragma unroll
        for (int m = 0; m < 3; m++) {
            const int ld0 = dg*24 + m*8;
            const int gd = (ld0 < 64) ? base0 + ld0 : base1 + (ld0 - 64);
            u16x8 v0 = *(const u16x8*)(r0 + ((gd*2) ^ sw0));
            u16x8 v1 = *(const u16x8*)(r1 + ((gd*2) ^ sw1));
            #pragma unroll
            for (int ee = 0; ee < 8; ee++) {
                const int d = ld0 + ee;
                *(u32*)(sm + d*512 + ((s0*2) ^ ((d&7)<<4)))
                    = (u32)v0[ee] | ((u32)v1[ee] << 16);
            }
        }
    }
    __syncthreads();

    // ---- phase 1: K'-half. wave=(jb, dh): j rows jb*64..+63, d cols dh*48..+47
    const int jb = w & 3, dh = w >> 2;
    f32x4 kacc[4][3];
    #pragma unroll
    for (int js = 0; js < 4; js++)
        #pragma unroll
        for (int ni = 0; ni < 3; ni++) kacc[js][ni] = (f32x4){0.f,0.f,0.f,0.f};
    #pragma unroll
    for (int ks = 0; ks < 8; ks++) {
        const int kb = ks*64 + lq*16;
        bf16x8 a[4];
        #pragma unroll
        for (int js = 0; js < 4; js++)
            a[js] = ((const bf16x8*)fw1f)[((jb*4 + js)*8 + ks)*64 + lane];
        #pragma unroll
        for (int ni = 0; ni < 3; ni++) {
            const int dr = dh*48 + ni*16 + l15;
            bf16x8 b = *(const bf16x8*)(sm + dr*512 + (kb ^ ((dr&7)<<4)));
            #pragma unroll
            for (int js = 0; js < 4; js++)
                kacc[js][ni] = __builtin_amdgcn_mfma_f32_16x16x32_bf16(
                    a[js], b, kacc[js][ni], 0,0,0);
        }
    }
    __syncthreads();   // all KZT reads done; KP overlays R0

    // ---- KP write: [256 j][pitch 208] bf16, no swizzle (208 spreads banks)
    #pragma unroll
    for (int js = 0; js < 4; js++)
        #pragma unroll
        for (int ni = 0; ni < 3; ni++) {
            const int d = dh*48 + ni*16 + l15;
            #pragma unroll
            for (int r = 0; r < 4; r++) {
                const int j = jb*64 + js*16 + lq*4 + r;
                *(u16*)(sm + j*208 + d*2) = f2bf(kacc[js][ni][r]);
            }
        }
    __syncthreads();

    // ---- af2: wave=(jb, qh) owns same 64 j rows, full 96 d (3 ks of 32)
    const int qh = w >> 2;
    bf16x8 af2[4][3];
    #pragma unroll
    for (int js = 0; js < 4; js++) {
        const int ar = jb*64 + js*16 + l15;
        #pragma unroll
        for (int ks = 0; ks < 3; ks++)
            af2[js][ks] = *(const bf16x8*)(sm + ar*208 + ks*64 + lq*16);
    }
    float f1v[4][4], f2v[4][4];
    #pragma unroll
    for (int js = 0; js < 4; js++)
        #pragma unroll
        for (int r = 0; r < 4; r++) {
            const int j = jb*64 + js*16 + lq*4 + r;
            f1v[js][r] = fb1[j]; f2v[js][r] = fw2[j];
        }

    // ---- phase 2: qt loop, 1 barrier/iter; E slabs [4 jb][2 sl][256 q] f32
    for (int qt = 0; qt < 4; qt++) {
        __syncthreads();   // drains stage(qt); buf[(qt+1)&1] free; af2/KP done
        if (qt < 3) stage_qz(qt+1, (qt+1)&1);
        const char* qb = sm + K34B_QZ + (qt&1)*K34B_QZSZ;
        #pragma unroll
        for (int qs = 0; qs < 2; qs++) {
            const int qoff = (qh*32 + qs*16 + l15)*208 + lq*16;
            f32x4 acc[4];
            // sl = 0: ks 0,1 (64-d source)
            #pragma unroll
            for (int js = 0; js < 4; js++) acc[js] = (f32x4){0.f,0.f,0.f,0.f};
            #pragma unroll
            for (int kk = 0; kk < 2; kk++) {
                bf16x8 b = *(const bf16x8*)(qb + qoff + kk*64);
                #pragma unroll
                for (int js = 0; js < 4; js++)
                    acc[js] = __builtin_amdgcn_mfma_f32_16x16x32_bf16(
                        af2[js][kk], b, acc[js], 0,0,0);
            }
            {
                float ep = 0.f;
                #pragma unroll
                for (int js = 0; js < 4; js++)
                    #pragma unroll
                    for (int r = 0; r < 4; r++)
                        ep += fmaxf(acc[js][r] + f1v[js][r], 0.f) * f2v[js][r];
                ep += __shfl_xor(ep, 16);
                ep += __shfl_xor(ep, 32);
                if (lane < 16)
                    ((float*)sm)[(jb*2 + 0)*256 + qt*64 + qh*32 + qs*16 + lane] = ep;
            }
            // sl = 1: ks 2 (32-d source)
            #pragma unroll
            for (int js = 0; js < 4; js++) acc[js] = (f32x4){0.f,0.f,0.f,0.f};
            {
                bf16x8 b = *(const bf16x8*)(qb + qoff + 128);
                #pragma unroll
                for (int js = 0; js < 4; js++)
                    acc[js] = __builtin_amdgcn_mfma_f32_16x16x32_bf16(
                        af2[js][2], b, acc[js], 0,0,0);
            }
            {
                float ep = 0.f;
                #pragma unroll
                for (int js = 0; js < 4; js++)
                    #pragma unroll
                    for (int r = 0; r < 4; r++)
                        ep += fmaxf(acc[js][r] + f1v[js][r], 0.f) * f2v[js][r];
                ep += __shfl_xor(ep, 16);
                ep += __shfl_xor(ep, 32);
                if (lane < 16)
                    ((float*)sm)[(jb*2 + 1)*256 + qt*64 + qh*32 + qs*16 + lane] = ep;
            }
        }
    }
    __syncthreads();
    {   // final reduce over 4 jb slabs; e src order: {item,pos,attr0,attr1}
        const int q = tid & 255, sl = tid >> 8;
        const float* el = (const float*)sm;
        float s = 0.f;
        #pragma unroll
        for (int j2 = 0; j2 < 4; j2++) s += el[(j2*2 + sl)*256 + q];
        const int gsrc = sl ? (2 + sp) : sp;
        e[((size_t)bh*256 + q)*4 + gsrc] = s;
    }
}

// ---------------------------------------------------------------------------
// K5B: gates -> mixed = (g.QZ) @ KZ^T -> row softmax -> PV -> ctx
// 52KB LDS -> 3 blocks/CU (12 waves/CU).
// ---------------------------------------------------------------------------
#define K5_KZ 24576
#define K5_VT 36864
#define K5_SMEM 53248

__global__ __launch_bounds__(256,3) void k5b(
    const u16* __restrict__ QZ, const u16* __restrict__ KZ,
    const u16* __restrict__ VT, const float* __restrict__ e,
    u16* __restrict__ ctx)
{
    extern __shared__ char sm[];
    const int tid = threadIdx.x, lane = tid & 63, w = tid >> 6;
    const int flat = blockIdx.x;
    const int xcd = flat & 7, idx = flat >> 3;   // idx < 256
    const int qt = idx & 3;
    const int bh = (idx >> 2) * 8 + xcd;
    const int q0 = qt*64;
    const int b = bh >> 3, h = bh & 7;
    const int kq16 = (lane>>4)*16;
    const char* QZc = (const char*)QZ + zrow(bh, q0);
    const char* KZc = (const char*)KZ + zrow(bh, 0);
    const char* VTc = (const char*)VT + (size_t)bh*32768;

    // initial staging: QZ 24KB + KZ chunk0 12KB + VT chunk0 8KB (verbatim)
    #pragma unroll
    for (int i = 0; i < 6; i++)
        gload16(QZc + i*4096 + tid*16, sm + i*4096 + tid*16);
    #pragma unroll
    for (int i = 0; i < 3; i++)
        gload16(KZc + i*4096 + tid*16, sm + K5_KZ + i*4096 + tid*16);
    #pragma unroll
    for (int i = 0; i < 2; i++)
        gload16(VTc + i*4096 + tid*16, sm + K5_VT + i*4096 + tid*16);
    __syncthreads();

    const int qrow = w*16 + (lane&15);
    float ga[4];
    {
        f32x4 ev = *(const f32x4*)(e + ((size_t)bh*256 + q0 + qrow)*4);
        float em = fmaxf(fmaxf(ev[0],ev[1]), fmaxf(ev[2],ev[3]));
        float s = 0.f;
        #pragma unroll
        for (int j = 0; j < 4; j++) { ga[j] = __expf(ev[j]-em); s += ga[j]; }
        const float gi = 1.f / s;
        #pragma unroll
        for (int j = 0; j < 4; j++) ga[j] *= gi;
    }
    const int asw = ((lane&15)&7) << 4;
    bf16x8 aF[6];
    #pragma unroll
    for (int ks = 0; ks < 6; ks++) {
        const int sidx = (ks<2)?0:(ks<4)?1:(ks<5)?2:3;
        u16x8 v = *(const u16x8*)(sm + qrow*384 + ((ks*64 + kq16) ^ asw));
        const float gg = ga[sidx];
        u16x8 pk;
        #pragma unroll
        for (int j = 0; j < 8; j++) pk[j] = f2bf(bf2f(v[j]) * gg);
        aF[ks] = __builtin_bit_cast(bf16x8, pk);
    }

    // ---- QK^T over 8 chunks of 32 k-rows, reg-prefetch swap (T14)
    f32x4 macc[16];
    #pragma unroll
    for (int t = 0; t < 16; t++) macc[t] = (f32x4){0.f,0.f,0.f,0.f};
    u16x8 kreg[3];
    #pragma unroll
    for (int kt = 0; kt < 8; kt++) {
        if (kt < 7) {
            #pragma unroll
            for (int j = 0; j < 3; j++)
                kreg[j] = *(const u16x8*)(KZc + (size_t)(kt+1)*12288
                                          + (tid + j*256)*16);
        }
        #pragma unroll
        for (int n2 = 0; n2 < 2; n2++) {
            const int kr = n2*16 + (lane&15);
            const int ksw = (kr&7)<<4;
            #pragma unroll
            for (int ks = 0; ks < 6; ks++) {
                bf16x8 bb = *(const bf16x8*)(sm + K5_KZ + kr*384
                                             + ((ks*64 + kq16) ^ ksw));
                macc[kt*2+n2] = __builtin_amdgcn_mfma_f32_16x16x32_bf16(
                    aF[ks], bb, macc[kt*2+n2], 0,0,0);
            }
        }
        if (kt < 7) {
            __syncthreads();
            #pragma unroll
            for (int j = 0; j < 3; j++)
                *(u16x8*)(sm + K5_KZ + (tid + j*256)*16) = kreg[j];
            __syncthreads();
        }
    }
    __syncthreads();   // all waves done with KZ/QZ before probs overlay

    // ---- softmax + probs write [64 q][512B swz] overlaying [0,32768)
    #pragma unroll
    for (int rr = 0; rr < 4; rr++) {
        float mx = -3.4e38f;
        #pragma unroll
        for (int t = 0; t < 16; t++) mx = fmaxf(mx, macc[t][rr]);
        #pragma unroll
        for (int msk = 1; msk < 16; msk <<= 1) mx = fmaxf(mx, __shfl_xor(mx, msk));
        float s = 0.f;
        #pragma unroll
        for (int t = 0; t < 16; t++) {
            float pv = __expf((macc[t][rr] - mx) * 0.125f);
            macc[t][rr] = pv; s += pv;
        }
        #pragma unroll
        for (int msk = 1; msk < 16; msk <<= 1) s += __shfl_xor(s, msk);
        const float inv = 1.f / s;
        const int orow = w*16 + (lane>>4)*4 + rr;
        const int osw = (orow&7)<<4;
        #pragma unroll
        for (int t = 0; t < 16; t++) {
            const int col = t*16 + (lane&15);
            *(u16*)(sm + orow*512 + ((col*2) ^ osw)) = f2bf(macc[t][rr]*inv);
        }
    }
    __syncthreads();

    // ---- PV: probs a-frags in regs; VT d-tiles double-buffered
    bf16x8 a[8];
    const int prow = w*16 + (lane&15);
    const int psw = ((lane&15)&7)<<4;
    #pragma unroll
    for (int ks = 0; ks < 8; ks++)
        a[ks] = *(const bf16x8*)(sm + prow*512 + ((ks*64 + kq16) ^ psw));

    const int orow = w*16 + (lane>>4)*4;
    #pragma unroll
    for (int n = 0; n < 4; n++) {
        if (n < 3) {   // prefetch next VT d-tile into other buf
            #pragma unroll
            for (int i = 0; i < 2; i++)
                gload16(VTc + (size_t)(n+1)*8192 + i*4096 + tid*16,
                        sm + K5_VT + ((n+1)&1)*8192 + i*4096 + tid*16);
        }
        f32x4 pacc = (f32x4){0.f,0.f,0.f,0.f};
        const char* vb = sm + K5_VT + (n&1)*8192;
        const int dl = lane & 15;
        const int vsw = (dl&7)<<4;
        #pragma unroll
        for (int ks = 0; ks < 8; ks++) {
            bf16x8 bb = *(const bf16x8*)(vb + dl*512 + ((ks*64 + kq16) ^ vsw));
            pacc = __builtin_amdgcn_mfma_f32_16x16x32_bf16(a[ks], bb, pacc, 0,0,0);
        }
        {
            const int d = n*16 + dl;
            #pragma unroll
            for (int r = 0; r < 4; r++) {
                const size_t grow = (size_t)b*256 + q0 + orow + r;
                ctx[grow*512 + h*64 + d] = f2bf(pacc[r]);
            }
        }
        if (n < 3) __syncthreads();   // drain prefetch; free read buf
    }
}

// ---------------------------------------------------------------------------
__global__ __launch_bounds__(256) void ln_k(float* __restrict__ x,
    const float* __restrict__ gamma, const float* __restrict__ beta)
{
    const int row = blockIdx.x*4 + (threadIdx.x >> 6);
    const int l = threadIdx.x & 63;
    float* p = x + (size_t)row*HDIM;
    f32x4 v0 = *(const f32x4*)(p + l*4);
    f32x4 v1 = *(const f32x4*)(p + 256 + l*4);
    float s = v0[0]+v0[1]+v0[2]+v0[3] + v1[0]+v1[1]+v1[2]+v1[3];
    #pragma unroll
    for (int msk = 1; msk < 64; msk <<= 1) s += __shfl_xor(s, msk);
    const float mu = s * (1.f/512.f);
    float vs = 0.f;
    #pragma unroll
    for (int j = 0; j < 4; j++) {
        float d0 = v0[j]-mu, d1 = v1[j]-mu;
        vs += d0*d0 + d1*d1;
    }
    #pragma unroll
    for (int msk = 1; msk < 64; msk <<= 1) vs += __shfl_xor(vs, msk);
    const float inv = 1.f / sqrtf(vs * (1.f/512.f) + 1e-12f);
    f32x4 o0, o1;
    #pragma unroll
    for (int j = 0; j < 4; j++) {
        o0[j] = gamma[l*4+j]     * (v0[j]-mu) * inv + beta[l*4+j];
        o1[j] = gamma[256+l*4+j] * (v1[j]-mu) * inv + beta[256+l*4+j];
    }
    *(f32x4*)(p + l*4) = o0;
    *(f32x4*)(p + 256 + l*4) = o1;
}

// ---------------------------------------------------------------------------
extern "C" void kernel_launch(void* const* d_in, const int* in_sizes, int n_in,
                              void* d_out, int out_size, void* d_ws, size_t ws_size,
                              hipStream_t stream)
{
    const float* input = (const float*)d_in[0];
    const float* attrt = (const float*)d_in[1];
    const float* pose  = (const float*)d_in[2];
    const float* Wq  = (const float*)d_in[3];  const float* bq  = (const float*)d_in[4];
    const float* Wk  = (const float*)d_in[5];  const float* bk  = (const float*)d_in[6];
    const float* Wv  = (const float*)d_in[7];  const float* bv  = (const float*)d_in[8];
    const float* Wqp = (const float*)d_in[9];  const float* bqp = (const float*)d_in[10];
    const float* Wkp = (const float*)d_in[11]; const float* bkp = (const float*)d_in[12];
    const float* Wqa = (const float*)d_in[13]; const float* bqa = (const float*)d_in[14];
    const float* Wka = (const float*)d_in[15]; const float* bka = (const float*)d_in[16];
    const float* fw1 = (const float*)d_in[17]; const float* fb1 = (const float*)d_in[18];
    const float* fw2 = (const float*)d_in[19]; /* fb2 cancels in softmax */
    const float* Wd  = (const float*)d_in[21]; const float* bd  = (const float*)d_in[22];
    const float* gamma = (const float*)d_in[23]; const float* beta = (const float*)d_in[24];

    char* ws = (char*)d_ws;
    u16*   wsQZ  = (u16*)(ws);                      // 50,331,648 B
    u16*   wsKZ  = (u16*)(ws + 50331648);           // 50,331,648 B
    u16*   wsTmp = (u16*)(ws + 100663296);          // 16,777,216 B (inB/poseB -> ctx)
    float* wsE   = (float*)(ws + 117440512);        //  2,097,152 B
    u16*   fw1b  = (u16*)(ws + 119537664);          //    131,072 B (fragment-ordered)
    u16*   dW    = (u16*)(ws + 119668736);          //  3,670,016 B (incl Wd)
    u16*   wsVT  = (u16*)d_out;                     // 16,777,216 B (dead before final GEMM)

    dim3 blk(256);

    cvtW_k<<<dim3(896), blk, 0, stream>>>(Wq, Wk, Wv, Wqp, Wkp, Wqa, Wka, Wd, dW);
    prep_fw1<<<dim3(128), dim3(64), 0, stream>>>(fw1, fw1b);

    cvt_k<<<dim3(2048), blk, 0, stream>>>(attrt, wsTmp, 524288);
    gemm128<6,1><<<dim3(1024), blk, 0, stream>>>(wsTmp, dW + 1310720,
        wsQZ, wsKZ, nullptr, bqa, bka, nullptr, nullptr, 1024, 256);
    cvt_k<<<dim3(2048), blk, 0, stream>>>(input, wsTmp, 1048576);
    gemm128<4,1><<<dim3(1536), blk, 0, stream>>>(wsTmp, dW,
        wsQZ, wsKZ, wsVT, bq, bk, bv, nullptr, 1536, 512);
    cvt_k<<<dim3(2048), blk, 0, stream>>>(pose, wsTmp, 1048576);
    gemm128<5,1><<<dim3(1024), blk, 0, stream>>>(wsTmp, dW + 786432,
        wsQZ, wsKZ, nullptr, bqp, bkp, nullptr, nullptr, 1024, 512);

    // merged K' + energy: 2 blocks per bh (source-pair split), 2 blocks/CU
    hipFuncSetAttribute(reinterpret_cast<const void*>(k34b),
                        hipFuncAttributeMaxDynamicSharedMemorySize, K34B_SMEM);
    k34b<<<dim3(NBH*2), dim3(512), K34B_SMEM, stream>>>(wsQZ, wsKZ, fw1b, fb1, fw2, wsE);

    hipFuncSetAttribute(reinterpret_cast<const void*>(k5b),
                        hipFuncAttributeMaxDynamicSharedMemorySize, K5_SMEM);
    k5b<<<dim3(2048), blk, K5_SMEM, stream>>>(wsQZ, wsKZ, wsVT, wsE, wsTmp);

    gemm128<2,1><<<dim3(512), blk, 0, stream>>>(wsTmp, dW + 1572864,
        d_out, nullptr, nullptr, bd, nullptr, nullptr, input, 512, 512);
    ln_k<<<dim3(BS/4), blk, 0, stream>>>((float*)d_out, gamma, beta);
}